// Round 2
// baseline (15887.004 us; speedup 1.0000x reference)
//
#include <hip/hip_runtime.h>

#define DEV __device__ __forceinline__

// WAGE quantizer: clip(round(x*128)/128, -127/128, 127/128). rintf = round-half-even (matches jnp.round).
DEV float wq8(float x) {
    float q = rintf(x * 128.0f) * 0.0078125f;
    return fminf(fmaxf(q, -0.9921875f), 0.9921875f);
}

// Order-preserving float<->uint encoding for atomicMax on signed floats.
DEV unsigned encf(float f) {
    unsigned u = __float_as_uint(f);
    return (u & 0x80000000u) ? ~u : (u | 0x80000000u);
}
DEV float decf(unsigned u) {
    return (u & 0x80000000u) ? __uint_as_float(u ^ 0x80000000u) : __uint_as_float(~u);
}

__global__ void k_quant(const float* __restrict__ src, float* __restrict__ dst, int n) {
    int i = blockIdx.x * 256 + threadIdx.x;
    if (i < n) dst[i] = wq8(src[i]);
}

__global__ void k_init_feat(unsigned* __restrict__ feat) {
    feat[threadIdx.x] = encf(-2.0f);   // any conv output q >= -127/128 > -2
}

// Accumulate one channel-segment of the (virtually concatenated+padded) input.
// CHK=false: interior fast path, no bounds predication.
template<int K, int OCT, bool CHK>
DEV void conv_accum(const float* __restrict__ sb, int cn,
                    const float* __restrict__ wc0, int wst,
                    int S, int ihb, int iwb, float* acc)
{
    const int SS = S * S;
    const float* wc = wc0;
    const float* pc = sb;
    for (int c = 0; c < cn; ++c, wc += K * K, pc += SS) {
        #pragma unroll
        for (int kh = 0; kh < K; ++kh) {
            const int ih = ihb + kh;
            if (CHK && ((unsigned)ih >= (unsigned)S)) continue;
            const float* prow = pc + ih * S;
            #pragma unroll
            for (int kw = 0; kw < K; ++kw) {
                const int iw = iwb + kw;
                if (CHK && ((unsigned)iw >= (unsigned)S)) continue;
                const float v = prow[iw];
                const int wi = kh * K + kw;
                #pragma unroll
                for (int t = 0; t < OCT; ++t)
                    acc[t] = fmaf(v, wc[(size_t)t * wst + wi], acc[t]);
            }
        }
    }
}

// Generic direct conv over up to 3 channel-concatenated sources, with
// pad_eff = conv_pad + cat_pad folded in. Output = first OH x OW (implements crop_like).
// MODE 0: dst = wq8(y)
// MODE 1: dst = (1 - wq8(y)) * res        (residual gate)
// MODE 2: atomicMax(feat[n*OC+oc], wq8(y))  (fused AdaptiveMaxPool)
template<int K, int OCT, int MODE>
__global__ void __launch_bounds__(256) k_conv(
    const float* __restrict__ s0, int c0n,
    const float* __restrict__ s1, int c1n,
    const float* __restrict__ s2, int c2n,
    int S, int padeff, int stride,
    const float* __restrict__ wq, int Cin,
    float* __restrict__ dst,
    unsigned* __restrict__ feat,
    const float* __restrict__ res,
    int OC, int OH, int OW)
{
    const int OCG = OC / OCT;
    const int nocg = blockIdx.y;
    const int n = nocg / OCG;
    const int ocg = nocg - n * OCG;
    const int sp = blockIdx.x * 256 + threadIdx.x;
    const int total_sp = OH * OW;
    const bool active = sp < total_sp;
    if (MODE != 2 && !active) return;

    float acc[OCT];
    #pragma unroll
    for (int t = 0; t < OCT; ++t) acc[t] = 0.f;
    const int oc0 = ocg * OCT;
    const int wst = Cin * K * K;

    if (active) {
        const int oh = sp / OW;
        const int ow = sp - oh * OW;
        const int ihb = oh * stride - padeff;
        const int iwb = ow * stride - padeff;
        const bool interior = (ihb >= 0) && (ihb + K <= S) && (iwb >= 0) && (iwb + K <= S);
        const float* w0 = wq + (size_t)oc0 * wst;
        const float* srcs[3] = { s0, s1, s2 };
        const int cnts[3] = { c0n, c1n, c2n };
        int cbase = 0;
        #pragma unroll
        for (int si = 0; si < 3; ++si) {
            const int cn = cnts[si];
            if (cn > 0) {
                const float* sb = srcs[si] + (size_t)n * cn * (S * S);
                const float* wc0 = w0 + (size_t)cbase * (K * K);
                if (interior) conv_accum<K, OCT, false>(sb, cn, wc0, wst, S, ihb, iwb, acc);
                else          conv_accum<K, OCT, true >(sb, cn, wc0, wst, S, ihb, iwb, acc);
                cbase += cn;
            }
        }
    }

    if constexpr (MODE == 0) {
        const size_t ob = ((size_t)n * OC + oc0) * total_sp + sp;
        #pragma unroll
        for (int t = 0; t < OCT; ++t) dst[ob + (size_t)t * total_sp] = wq8(acc[t]);
    } else if constexpr (MODE == 1) {
        const size_t ob = ((size_t)n * OC + oc0) * total_sp + sp;
        #pragma unroll
        for (int t = 0; t < OCT; ++t) {
            const size_t o = ob + (size_t)t * total_sp;
            dst[o] = (1.0f - wq8(acc[t])) * res[o];
        }
    } else {
        __shared__ float red[256];
        #pragma unroll
        for (int t = 0; t < OCT; ++t) {
            float q = active ? wq8(acc[t]) : -2.0f;
            __syncthreads();
            red[threadIdx.x] = q;
            __syncthreads();
            for (int off = 128; off > 0; off >>= 1) {
                if ((int)threadIdx.x < off)
                    red[threadIdx.x] = fmaxf(red[threadIdx.x], red[threadIdx.x + off]);
                __syncthreads();
            }
            if (threadIdx.x == 0) atomicMax(&feat[n * OC + oc0 + t], encf(red[0]));
        }
    }
}

// out[n] = wq8( sum_c feat[n,c] * wq8(wfc[c]) ) — exact in fp32 (1/16384 grid, |sum|<=32)
__global__ void k_fc(const unsigned* __restrict__ feat, const float* __restrict__ wfc,
                     float* __restrict__ out) {
    int n = threadIdx.x;
    if (n < 8) {
        float s = 0.f;
        for (int c = 0; c < 32; ++c) s += decf(feat[n * 32 + c]) * wq8(wfc[c]);
        out[n] = wq8(s);
    }
}

extern "C" void kernel_launch(void* const* d_in, const int* in_sizes, int n_in,
                              void* d_out, int out_size, void* d_ws, size_t ws_size,
                              hipStream_t stream)
{
    (void)in_sizes; (void)n_in; (void)out_size; (void)ws_size;
    const float* x = (const float*)d_in[0];
    const float* wsrc[15];
    for (int i = 0; i < 15; ++i) wsrc[i] = (const float*)d_in[1 + i];
    const float* wfc = (const float*)d_in[16];
    float* out = (float*)d_out;

    // element counts, d_in order: w1 w2 w3 w4 wr11 wr12 wr21 wr22 wd3 wd2 wd1 wu43 wu32 wu21 wu10
    static const int wn[15] = {
        64*4*9, 128*64*9, 256*128*9, 512*256*9,
        512*512*9, 512*512*9, 512*512*9, 512*512*9,
        128*512*16, 64*416*16, 4*224*16,
        32*512*16, 32*416*16, 32*224*16, 32*100*16
    };

    float* ws = (float*)d_ws;
    size_t off = 0;
    auto alloc = [&](size_t nelem) {
        float* p = ws + off;
        off += (nelem + 63) & ~(size_t)63;
        return p;
    };

    float* wqp[15];
    for (int i = 0; i < 15; ++i) wqp[i] = alloc(wn[i]);

    float* c1b  = alloc((size_t)8*64*128*128);
    float* c2b  = alloc((size_t)8*128*64*64);
    float* c3b  = alloc((size_t)8*256*32*32);
    float* c4b  = alloc((size_t)8*512*16*16);
    float* r11b = alloc((size_t)8*512*16*16);  // also reused for r21
    float* r12b = alloc((size_t)8*512*16*16);
    float* r22b = alloc((size_t)8*512*16*16);
    float* f4b  = alloc((size_t)8*32*32*32);
    float* d3b  = alloc((size_t)8*128*32*32);
    float* f3b  = alloc((size_t)8*32*64*64);
    float* d2b  = alloc((size_t)8*64*64*64);
    float* f2b  = alloc((size_t)8*32*128*128);
    float* d1b  = alloc((size_t)8*4*128*128);
    unsigned* featb = (unsigned*)alloc(256);
    // total ~165 MB of ws

    for (int i = 0; i < 15; ++i)
        k_quant<<<dim3((unsigned)((wn[i] + 255) / 256)), dim3(256), 0, stream>>>(wsrc[i], wqp[i], wn[i]);

    #define CONV(Kv, OCTv, MODEv, a0, n0, a1, n1c, a2, n2c, Sv, PADv, STRv, W, CINv, DST, FEAT, RES, OCv, OHv, OWv) \
        do { dim3 g((unsigned)(((OHv)*(OWv) + 255) / 256), (unsigned)(8 * ((OCv) / (OCTv)))); \
             k_conv<Kv, OCTv, MODEv><<<g, dim3(256), 0, stream>>>(a0, n0, a1, n1c, a2, n2c, \
                 Sv, PADv, STRv, W, CINv, DST, FEAT, RES, OCv, OHv, OWv); } while (0)

    // encoder: K=3, stride 2, pad 1
    CONV(3, 8, 0, x,    4,  nullptr,0, nullptr,0, 256, 1, 2, wqp[0],  4,   c1b,  nullptr, nullptr,  64, 128, 128);
    CONV(3, 8, 0, c1b,  64, nullptr,0, nullptr,0, 128, 1, 2, wqp[1],  64,  c2b,  nullptr, nullptr, 128,  64,  64);
    CONV(3, 8, 0, c2b, 128, nullptr,0, nullptr,0,  64, 1, 2, wqp[2], 128,  c3b,  nullptr, nullptr, 256,  32,  32);
    CONV(3, 8, 0, c3b, 256, nullptr,0, nullptr,0,  32, 1, 2, wqp[3], 256,  c4b,  nullptr, nullptr, 512,  16,  16);
    // residual blocks: K=3, stride 1, pad 1
    CONV(3, 8, 0, c4b, 512, nullptr,0, nullptr,0,  16, 1, 1, wqp[4], 512, r11b,  nullptr, nullptr, 512,  16,  16);
    CONV(3, 8, 1, r11b,512, nullptr,0, nullptr,0,  16, 1, 1, wqp[5], 512, r12b,  nullptr, c4b,     512,  16,  16);
    CONV(3, 8, 0, r12b,512, nullptr,0, nullptr,0,  16, 1, 1, wqp[6], 512, r11b,  nullptr, nullptr, 512,  16,  16);
    CONV(3, 8, 1, r11b,512, nullptr,0, nullptr,0,  16, 1, 1, wqp[7], 512, r22b,  nullptr, r12b,    512,  16,  16);
    // decoder: K=4, stride 1; pad_eff = conv_pad(2) + cat_pad; crop = compute first OHxOW
    CONV(4, 8, 0, r22b,512, nullptr,0, nullptr,0,  16, 10, 1, wqp[11], 512, f4b, nullptr, nullptr,  32,  32,  32);
    CONV(4, 8, 0, r22b,512, nullptr,0, nullptr,0,  16, 10, 1, wqp[8],  512, d3b, nullptr, nullptr, 128,  32,  32);
    CONV(4, 8, 0, c3b, 256, d3b,128, f4b,32,       32, 18, 1, wqp[12], 416, f3b, nullptr, nullptr,  32,  64,  64);
    CONV(4, 8, 0, c3b, 256, d3b,128, f4b,32,       32, 18, 1, wqp[9],  416, d2b, nullptr, nullptr,  64,  64,  64);
    CONV(4, 8, 0, c2b, 128, d2b, 64, f3b,32,       64, 34, 1, wqp[13], 224, f2b, nullptr, nullptr,  32, 128, 128);
    CONV(4, 4, 0, c2b, 128, d2b, 64, f3b,32,       64, 34, 1, wqp[10], 224, d1b, nullptr, nullptr,   4, 128, 128);
    // u10 + fused global max-pool
    k_init_feat<<<dim3(1), dim3(256), 0, stream>>>(featb);
    CONV(4, 8, 2, c1b,  64, d1b,  4, f2b,32,      128, 66, 1, wqp[14], 100, (float*)nullptr, featb, nullptr, 32, 257, 257);
    // FC 32 -> 1
    k_fc<<<dim3(1), dim3(64), 0, stream>>>(featb, wfc, out);
    #undef CONV
}

// Round 3
// 1500.779 us; speedup vs baseline: 10.5858x; 10.5858x over previous
//
#include <hip/hip_runtime.h>

#define DEV __device__ __forceinline__

typedef __attribute__((ext_vector_type(8))) short short8;
typedef __attribute__((ext_vector_type(4))) float f32x4;

// WAGE quantizer: clip(round(x*128)/128, +-127/128). rintf = RNE = jnp.round.
DEV float wq8(float x) {
    float q = rintf(x * 128.0f) * 0.0078125f;
    return fminf(fmaxf(q, -0.9921875f), 0.9921875f);
}
// f32 -> bf16 bits (RNE; no NaN/Inf in this workload) and back.
DEV unsigned short f2bf(float x) {
    unsigned u = __float_as_uint(x);
    return (unsigned short)((u + 0x7FFFu + ((u >> 16) & 1u)) >> 16);
}
DEV float bf2f(unsigned short h) { return __uint_as_float(((unsigned)h) << 16); }
// exact hi/mid/lo bf16 split of f32 (s-th piece)
DEV unsigned short bfsplit_u(float x, int s) {
    unsigned short h0 = f2bf(x);
    if (s == 0) return h0;
    float r1 = x - bf2f(h0);
    unsigned short h1 = f2bf(r1);
    if (s == 1) return h1;
    return f2bf(r1 - bf2f(h1));
}
// order-preserving float<->uint for atomicMax
DEV unsigned encf(float f) { unsigned u = __float_as_uint(f); return (u & 0x80000000u) ? ~u : (u | 0x80000000u); }
DEV float decf(unsigned u) { return (u & 0x80000000u) ? __uint_as_float(u ^ 0x80000000u) : __uint_as_float(~u); }

// Pack OIHW f32 weights -> wq8 -> bf16 MFMA B-fragment order:
// dst[((kpos*nch+ch)*noct+oct)*64 + lane] = uint4 of 8 bf16, element e -> k = (e<4? g*4+e : 16+g*4+e-4)
__global__ void __launch_bounds__(256) k_pack(const float* __restrict__ w, uint4* __restrict__ dst,
                                              int OC, int Cin, int K, int nch, int noct, int total) {
    const int gi = blockIdx.x * 256 + threadIdx.x;
    if (gi >= total) return;
    const int lane = gi & 63; int t = gi >> 6;
    const int oct = t % noct; t /= noct;
    const int ch = t % nch; const int kpos = t / nch;
    const int kh = kpos / K, kw = kpos % K;
    const int oc = oct * 16 + (lane & 15), g = lane >> 4;
    unsigned short h[8];
    #pragma unroll
    for (int e = 0; e < 8; ++e) {
        const int kk = (e < 4) ? g * 4 + e : 16 + g * 4 + (e - 4);
        const int cin = ch * 32 + kk;
        float v = 0.f;
        if (oc < OC && cin < Cin) v = wq8(w[((size_t)(oc * Cin + cin) * K + kh) * K + kw]);
        h[e] = f2bf(v);
    }
    uint4 u;
    u.x = h[0] | ((unsigned)h[1] << 16); u.y = h[2] | ((unsigned)h[3] << 16);
    u.z = h[4] | ((unsigned)h[5] << 16); u.w = h[6] | ((unsigned)h[7] << 16);
    dst[gi] = u;
}

// conv1: Cin=4, f32 NCHW input x, stride2 pad1 -> c1 NHWC bf16 (cheap vector path)
__global__ void __launch_bounds__(256) k_conv1(const float* __restrict__ x, const float* __restrict__ w1,
                                               unsigned short* __restrict__ c1) {
    const int t = blockIdx.x * 256 + threadIdx.x;
    const int oc = t & 63; int idx = t >> 6;
    const int ow = idx & 127; idx >>= 7;
    const int oh = idx & 127; idx >>= 7;
    const int n = idx;
    float a = 0.f;
    #pragma unroll
    for (int c = 0; c < 4; ++c)
    #pragma unroll
    for (int kh = 0; kh < 3; ++kh) {
        const int ih = oh * 2 - 1 + kh;
        if ((unsigned)ih >= 256u) continue;
        #pragma unroll
        for (int kw = 0; kw < 3; ++kw) {
            const int iw = ow * 2 - 1 + kw;
            if ((unsigned)iw >= 256u) continue;
            a = fmaf(x[((size_t)(n * 4 + c) * 256 + ih) * 256 + iw],
                     wq8(w1[((oc * 4 + c) * 3 + kh) * 3 + kw]), a);
        }
    }
    c1[((size_t)(n * 128 + oh) * 128 + ow) * 64 + oc] = f2bf(wq8(a));
}

__global__ void k_init_feat(unsigned* __restrict__ feat) { feat[threadIdx.x] = encf(-2.0f); }

__global__ void k_fc(const unsigned* __restrict__ feat, const float* __restrict__ wfc,
                     float* __restrict__ out) {
    int n = threadIdx.x;
    if (n < 8) {
        float s = 0.f;
        for (int c = 0; c < 32; ++c) s += decf(feat[n * 32 + c]) * wq8(wfc[c]);
        out[n] = wq8(s);
    }
}

// Implicit-GEMM MFMA conv. NHWC in/out. Up to 3 channel-concatenated sources,
// pad_eff folded into staging, crop via OH/OW. 4 waves: wave w=(wm=w%WM, wn=w/WM);
// per wave 32sp x (BN*16)oc via mfma_f32_16x16x32_bf16.
// MODE 0: dst(bf16) = wq8(y);  MODE 1: dstf(f32) = (1-wq8(y))*res;  MODE 2: feat = max over sp.
// F32S: sources are f32, staged as exact bf16 split s (NSPLIT passes).
template<int K, int STR, int WM, int WN, int BN, int NSPLIT, int MODE, int RESF, bool F32S>
__global__ void __launch_bounds__(256) k_mconv(
    const void* __restrict__ s0, int c0n,
    const void* __restrict__ s1, int c1n,
    const void* __restrict__ s2, int c2n,
    int S, int padeff,
    const uint4* __restrict__ wqp, int nch, int noct,
    unsigned short* __restrict__ dst, float* __restrict__ dstf,
    const void* __restrict__ res, unsigned* __restrict__ feat,
    int OC, int OH, int OW, int TILES_W)
{
    constexpr int TH = WM * 4, TW = 8;
    constexpr int RH = (TH - 1) * STR + K, RW = (TW - 1) * STR + K;
    constexpr int NQ = RH * RW * 8;          // quads of 4 bf16 (8B)
    __shared__ uint2 ldsq[NQ];
    __shared__ float sred[4][16];

    const int tid = threadIdx.x;
    const int lane = tid & 63, w = tid >> 6;
    const int wm = w % WM, wn = w / WM;
    const int l15 = lane & 15, g = lane >> 4;
    const int n = blockIdx.z;
    const int tileh = blockIdx.x / TILES_W, tilew = blockIdx.x % TILES_W;
    const int oh0 = tileh * TH, ow0 = tilew * TW;
    const int ih0 = oh0 * STR - padeff, iw0 = ow0 * STR - padeff;
    const int blk_oct0 = blockIdx.y * (WN * BN);
    const int Cin_tot = c0n + c1n + c2n;

    f32x4 acc[2][BN];
    #pragma unroll
    for (int am = 0; am < 2; ++am)
        #pragma unroll
        for (int bn = 0; bn < BN; ++bn) acc[am][bn] = (f32x4){0.f, 0.f, 0.f, 0.f};

    for (int s = 0; s < NSPLIT; ++s)
    for (int ch = 0; ch < nch; ++ch) {
        __syncthreads();
        // ---- stage input region (RH x RW x 32cin), quad-swizzled (q ^= c&7) ----
        for (int idx = tid; idx < NQ; idx += 256) {
            const int q = idx & 7; const int rc = idx >> 3;
            const int c = rc % RW, r = rc / RW;
            const int ih = ih0 + r, iw = iw0 + c;
            const int cin = ch * 32 + q * 4;
            uint2 v; v.x = 0u; v.y = 0u;
            if (((unsigned)ih < (unsigned)S) && ((unsigned)iw < (unsigned)S) && cin < Cin_tot) {
                const size_t pix = ((size_t)n * S + ih) * S + iw;
                const void* sp_; int loc, segC;
                if (cin < c0n)             { sp_ = s0; loc = cin;             segC = c0n; }
                else if (cin < c0n + c1n)  { sp_ = s1; loc = cin - c0n;       segC = c1n; }
                else                       { sp_ = s2; loc = cin - c0n - c1n; segC = c2n; }
                if (F32S) {
                    const float* p = (const float*)sp_ + pix * segC + loc;
                    unsigned short h0 = bfsplit_u(p[0], s), h1 = bfsplit_u(p[1], s);
                    unsigned short h2 = bfsplit_u(p[2], s), h3 = bfsplit_u(p[3], s);
                    v.x = (unsigned)h0 | ((unsigned)h1 << 16);
                    v.y = (unsigned)h2 | ((unsigned)h3 << 16);
                } else {
                    v = *(const uint2*)((const unsigned short*)sp_ + pix * segC + loc);
                }
            }
            ldsq[(r * RW + c) * 8 + (q ^ (c & 7))] = v;
        }
        __syncthreads();
        // ---- K*K kernel positions, 2xBN MFMAs each ----
        #pragma unroll
        for (int kh = 0; kh < K; ++kh)
        #pragma unroll
        for (int kw = 0; kw < K; ++kw) {
            const int kpos = kh * K + kw;
            short8 bfr[BN];
            #pragma unroll
            for (int bn = 0; bn < BN; ++bn) {
                const int oct = blk_oct0 + wn * BN + bn;
                union { uint4 u; short8 s8; } bu;
                bu.u = wqp[((size_t)(kpos * nch + ch) * noct + oct) * 64 + lane];
                bfr[bn] = bu.s8;
            }
            short8 afr[2];
            #pragma unroll
            for (int am = 0; am < 2; ++am) {
                const int sp = wm * 32 + am * 16 + l15;
                const int r = (sp >> 3) * STR + kh, c = (sp & 7) * STR + kw;
                const int base = (r * RW + c) * 8, cs = c & 7;
                union { uint2 u[2]; short8 s8; } au;
                au.u[0] = ldsq[base + (g ^ cs)];
                au.u[1] = ldsq[base + ((g + 4) ^ cs)];
                afr[am] = au.s8;
            }
            #pragma unroll
            for (int am = 0; am < 2; ++am)
                #pragma unroll
                for (int bn = 0; bn < BN; ++bn)
                    acc[am][bn] = __builtin_amdgcn_mfma_f32_16x16x32_bf16(afr[am], bfr[bn], acc[am][bn], 0, 0, 0);
        }
    }

    // ---- epilogue ----
    if (MODE == 2) {
        float m = -2.0f;   // BN==1 in MODE2 usage
        #pragma unroll
        for (int am = 0; am < 2; ++am)
            #pragma unroll
            for (int rg = 0; rg < 4; ++rg) {
                const int sp = wm * 32 + am * 16 + g * 4 + rg;
                const int oh = oh0 + (sp >> 3), ow = ow0 + (sp & 7);
                float v = (oh < OH && ow < OW) ? wq8(acc[am][0][rg]) : -2.0f;
                m = fmaxf(m, v);
            }
        m = fmaxf(m, __shfl_xor(m, 16));
        m = fmaxf(m, __shfl_xor(m, 32));
        if (lane < 16) sred[w][l15] = m;
        __syncthreads();
        if (tid < 32) {
            const int wn2 = tid >> 4, l = tid & 15;
            float mm = sred[wn2 * WM + 0][l];
            #pragma unroll
            for (int i = 1; i < WM; ++i) mm = fmaxf(mm, sred[wn2 * WM + i][l]);
            atomicMax(&feat[n * 32 + (blk_oct0 + wn2) * 16 + l], encf(mm));
        }
    } else {
        #pragma unroll
        for (int am = 0; am < 2; ++am)
        #pragma unroll
        for (int bn = 0; bn < BN; ++bn)
        #pragma unroll
        for (int rg = 0; rg < 4; ++rg) {
            const int sp = wm * 32 + am * 16 + g * 4 + rg;
            const int oh = oh0 + (sp >> 3), ow = ow0 + (sp & 7);
            const int oc = (blk_oct0 + wn * BN + bn) * 16 + l15;
            if (oh < OH && ow < OW && oc < OC) {
                const size_t o = ((size_t)(n * OH + oh) * OW + ow) * OC + oc;
                const float y = wq8(acc[am][bn][rg]);
                if (MODE == 0) dst[o] = f2bf(y);
                else {
                    float rv = (RESF == 1) ? bf2f(((const unsigned short*)res)[o]) : ((const float*)res)[o];
                    dstf[o] = (1.0f - y) * rv;
                }
            }
        }
    }
}

extern "C" void kernel_launch(void* const* d_in, const int* in_sizes, int n_in,
                              void* d_out, int out_size, void* d_ws, size_t ws_size,
                              hipStream_t stream)
{
    (void)in_sizes; (void)n_in; (void)out_size; (void)ws_size;
    const float* x = (const float*)d_in[0];
    const float* wfc = (const float*)d_in[16];
    float* out = (float*)d_out;

    char* ws = (char*)d_ws;
    size_t off = 0;
    auto alloc = [&](size_t bytes) { char* p = ws + off; off += (bytes + 255) & ~(size_t)255; return p; };

    // packed weights: {d_in idx, OC, Cin, K, nch, noct}
    struct PL { int win, OC, Cin, K, nch, noct; };
    static const PL pl[14] = {
        {2, 128,  64, 3,  2,  8},   // 0 conv2
        {3, 256, 128, 3,  4, 16},   // 1 conv3
        {4, 512, 256, 3,  8, 32},   // 2 conv4
        {5, 512, 512, 3, 16, 32},   // 3 r11
        {6, 512, 512, 3, 16, 32},   // 4 r12
        {7, 512, 512, 3, 16, 32},   // 5 r21
        {8, 512, 512, 3, 16, 32},   // 6 r22
        {9, 128, 512, 4, 16,  8},   // 7 wd3
        {10, 64, 416, 4, 13,  4},   // 8 wd2
        {11,  4, 224, 4,  7,  1},   // 9 wd1
        {12, 32, 512, 4, 16,  2},   // 10 wu43
        {13, 32, 416, 4, 13,  2},   // 11 wu32
        {14, 32, 224, 4,  7,  2},   // 12 wu21
        {15, 32, 100, 4,  4,  2}};  // 13 wu10
    uint4* wp[14]; int wtot[14];
    for (int i = 0; i < 14; ++i) {
        wtot[i] = pl[i].K * pl[i].K * pl[i].nch * pl[i].noct * 64;
        wp[i] = (uint4*)alloc((size_t)wtot[i] * 16);
    }

    unsigned short* c1b  = (unsigned short*)alloc((size_t)8*128*128*64 * 2);
    unsigned short* c2b  = (unsigned short*)alloc((size_t)8*64*64*128 * 2);
    unsigned short* c3b  = (unsigned short*)alloc((size_t)8*32*32*256 * 2);
    unsigned short* c4b  = (unsigned short*)alloc((size_t)8*16*16*512 * 2);
    unsigned short* r11b = (unsigned short*)alloc((size_t)8*16*16*512 * 2);  // also r21
    float*          r12f = (float*)alloc((size_t)8*16*16*512 * 4);
    float*          r22f = (float*)alloc((size_t)8*16*16*512 * 4);
    unsigned short* f4b  = (unsigned short*)alloc((size_t)8*32*32*32 * 2);
    unsigned short* d3b  = (unsigned short*)alloc((size_t)8*32*32*128 * 2);
    unsigned short* f3b  = (unsigned short*)alloc((size_t)8*64*64*32 * 2);
    unsigned short* d2b  = (unsigned short*)alloc((size_t)8*64*64*64 * 2);
    unsigned short* f2b  = (unsigned short*)alloc((size_t)8*128*128*32 * 2);
    unsigned short* d1b  = (unsigned short*)alloc((size_t)8*128*128*4 * 2);
    unsigned*       featb = (unsigned*)alloc(256 * 4);

    for (int i = 0; i < 14; ++i)
        k_pack<<<dim3((wtot[i] + 255) / 256), dim3(256), 0, stream>>>(
            (const float*)d_in[pl[i].win], wp[i], pl[i].OC, pl[i].Cin, pl[i].K, pl[i].nch, pl[i].noct, wtot[i]);

    k_conv1<<<dim3(8*128*128*64/256), dim3(256), 0, stream>>>(x, (const float*)d_in[1], c1b);

    // encoder
    k_mconv<3,2,2,2,2,1,0,0,false><<<dim3(64,2,8), 256, 0, stream>>>(
        c1b,64, nullptr,0, nullptr,0, 128,1, wp[0],2,8,  c2b,nullptr,nullptr,nullptr, 128,64,64, 8);
    k_mconv<3,2,2,2,2,1,0,0,false><<<dim3(16,4,8), 256, 0, stream>>>(
        c2b,128, nullptr,0, nullptr,0, 64,1, wp[1],4,16, c3b,nullptr,nullptr,nullptr, 256,32,32, 4);
    k_mconv<3,2,2,2,2,1,0,0,false><<<dim3(4,8,8), 256, 0, stream>>>(
        c3b,256, nullptr,0, nullptr,0, 32,1, wp[2],8,32, c4b,nullptr,nullptr,nullptr, 512,16,16, 2);
    // residual blocks
    k_mconv<3,1,2,2,2,1,0,0,false><<<dim3(4,8,8), 256, 0, stream>>>(
        c4b,512, nullptr,0, nullptr,0, 16,1, wp[3],16,32, r11b,nullptr,nullptr,nullptr, 512,16,16, 2);
    k_mconv<3,1,2,2,2,1,1,1,false><<<dim3(4,8,8), 256, 0, stream>>>(
        r11b,512, nullptr,0, nullptr,0, 16,1, wp[4],16,32, nullptr,r12f,c4b,nullptr, 512,16,16, 2);
    k_mconv<3,1,2,2,2,2,0,0,true><<<dim3(4,8,8), 256, 0, stream>>>(
        r12f,512, nullptr,0, nullptr,0, 16,1, wp[5],16,32, r11b,nullptr,nullptr,nullptr, 512,16,16, 2);
    k_mconv<3,1,2,2,2,1,1,2,false><<<dim3(4,8,8), 256, 0, stream>>>(
        r11b,512, nullptr,0, nullptr,0, 16,1, wp[6],16,32, nullptr,r22f,r12f,nullptr, 512,16,16, 2);
    // decoder level 3 (src r22 f32, 3-way split)
    k_mconv<4,1,2,2,1,3,0,0,true><<<dim3(16,1,8), 256, 0, stream>>>(
        r22f,512, nullptr,0, nullptr,0, 16,10, wp[10],16,2, f4b,nullptr,nullptr,nullptr, 32,32,32, 4);
    k_mconv<4,1,2,2,2,3,0,0,true><<<dim3(16,2,8), 256, 0, stream>>>(
        r22f,512, nullptr,0, nullptr,0, 16,10, wp[7],16,8, d3b,nullptr,nullptr,nullptr, 128,32,32, 4);
    // level 2 (cat3 = c3|d3|f4, S=32, padeff=18)
    k_mconv<4,1,2,2,1,1,0,0,false><<<dim3(64,1,8), 256, 0, stream>>>(
        c3b,256, d3b,128, f4b,32, 32,18, wp[11],13,2, f3b,nullptr,nullptr,nullptr, 32,64,64, 8);
    k_mconv<4,1,2,2,2,1,0,0,false><<<dim3(64,1,8), 256, 0, stream>>>(
        c3b,256, d3b,128, f4b,32, 32,18, wp[8],13,4, d2b,nullptr,nullptr,nullptr, 64,64,64, 8);
    // level 1 (cat2 = c2|d2|f3, S=64, padeff=34)
    k_mconv<4,1,2,2,1,1,0,0,false><<<dim3(256,1,8), 256, 0, stream>>>(
        c2b,128, d2b,64, f3b,32, 64,34, wp[12],7,2, f2b,nullptr,nullptr,nullptr, 32,128,128, 16);
    k_mconv<4,1,4,1,1,1,0,0,false><<<dim3(128,1,8), 256, 0, stream>>>(
        c2b,128, d2b,64, f3b,32, 64,34, wp[9],7,1, d1b,nullptr,nullptr,nullptr, 4,128,128, 16);
    // level 0: u10 + fused global max-pool (cat1 = c1|d1|f2, S=128, padeff=66)
    k_init_feat<<<dim3(1), dim3(256), 0, stream>>>(featb);
    k_mconv<4,1,2,2,1,1,2,0,false><<<dim3(1089,1,8), 256, 0, stream>>>(
        c1b,64, d1b,4, f2b,32, 128,66, wp[13],4,2, nullptr,nullptr,nullptr,featb, 32,257,257, 33);
    // FC 32 -> 1
    k_fc<<<dim3(1), dim3(64), 0, stream>>>(featb, wfc, out);
}

// Round 4
// 999.958 us; speedup vs baseline: 15.8877x; 1.5008x over previous
//
#include <hip/hip_runtime.h>

#define DEV __device__ __forceinline__

typedef __attribute__((ext_vector_type(8))) short short8;
typedef __attribute__((ext_vector_type(4))) float f32x4;

// WAGE quantizer: clip(round(x*128)/128, +-127/128). rintf = RNE = jnp.round.
DEV float wq8(float x) {
    float q = rintf(x * 128.0f) * 0.0078125f;
    return fminf(fmaxf(q, -0.9921875f), 0.9921875f);
}
DEV unsigned short f2bf(float x) {
    unsigned u = __float_as_uint(x);
    return (unsigned short)((u + 0x7FFFu + ((u >> 16) & 1u)) >> 16);
}
DEV float bf2f(unsigned short h) { return __uint_as_float(((unsigned)h) << 16); }
DEV unsigned encf(float f) { unsigned u = __float_as_uint(f); return (u & 0x80000000u) ? ~u : (u | 0x80000000u); }
DEV float decf(unsigned u) { return (u & 0x80000000u) ? __uint_as_float(u ^ 0x80000000u) : __uint_as_float(~u); }

// Merged weight pack. oc < OC0 -> w0[oc], else oc < OC0+OC1 -> w1[oc-OC0], else 0.
// cin duplication for hi|lo concat sources: CinT may be 2*CinW (cin >= CinW reads cin-CinW).
// Fragment element e -> k = (e<4 ? g*4+e : 16+g*4+e-4), oc = oct*16 + (lane&15), g = lane>>4.
__global__ void __launch_bounds__(256) k_pack(
    const float* __restrict__ w0, int OC0, const float* __restrict__ w1, int OC1,
    int CinW, int CinT, int K, int nch32, int noct, int total)
{
    const int gi = blockIdx.x * 256 + threadIdx.x;
    if (gi >= total) return;
    const int lane = gi & 63; int t = gi >> 6;
    const int oct = t % noct; t /= noct;
    const int ch = t % nch32; const int kpos = t / nch32;
    const int kh = kpos / K, kw = kpos % K;
    const int oc = oct * 16 + (lane & 15), g = lane >> 4;
    const float* src = nullptr; int oci = 0;
    if (oc < OC0) { src = w0; oci = oc; }
    else if (oc < OC0 + OC1) { src = w1; oci = oc - OC0; }
    unsigned short h[8];
    #pragma unroll
    for (int e = 0; e < 8; ++e) {
        const int kk = (e < 4) ? g * 4 + e : 16 + g * 4 + (e - 4);
        const int cin = ch * 32 + kk;
        float v = 0.f;
        if (src != nullptr && cin < CinT) {
            const int cw = (cin >= CinW) ? cin - CinW : cin;
            v = wq8(src[((size_t)(oci * CinW + cw) * K + kh) * K + kw]);
        }
        h[e] = f2bf(v);
    }
    uint4 u;
    u.x = h[0] | ((unsigned)h[1] << 16); u.y = h[2] | ((unsigned)h[3] << 16);
    u.z = h[4] | ((unsigned)h[5] << 16); u.w = h[6] | ((unsigned)h[7] << 16);
    ((uint4*)nullptr, 0);  // no-op
    // dst passed via w1? no — separate param:
    // (kept simple: dst is global param below)
    extern __shared__ char _unused[];
    (void)_unused;
    // real store:
    // moved to parameter list version below
    // (this function body is replaced — see k_pack2)
}

// actual pack kernel (k_pack above kept minimal-compilable is not used)
__global__ void __launch_bounds__(256) k_pack2(
    const float* __restrict__ w0, int OC0, const float* __restrict__ w1, int OC1,
    int CinW, int CinT, int K, int nch32, int noct, uint4* __restrict__ dst, int total)
{
    const int gi = blockIdx.x * 256 + threadIdx.x;
    if (gi >= total) return;
    const int lane = gi & 63; int t = gi >> 6;
    const int oct = t % noct; t /= noct;
    const int ch = t % nch32; const int kpos = t / nch32;
    const int kh = kpos / K, kw = kpos % K;
    const int oc = oct * 16 + (lane & 15), g = lane >> 4;
    const float* src = nullptr; int oci = 0;
    if (oc < OC0) { src = w0; oci = oc; }
    else if (oc < OC0 + OC1) { src = w1; oci = oc - OC0; }
    unsigned short h[8];
    #pragma unroll
    for (int e = 0; e < 8; ++e) {
        const int kk = (e < 4) ? g * 4 + e : 16 + g * 4 + (e - 4);
        const int cin = ch * 32 + kk;
        float v = 0.f;
        if (src != nullptr && cin < CinT) {
            const int cw = (cin >= CinW) ? cin - CinW : cin;
            v = wq8(src[((size_t)(oci * CinW + cw) * K + kh) * K + kw]);
        }
        h[e] = f2bf(v);
    }
    uint4 u;
    u.x = h[0] | ((unsigned)h[1] << 16); u.y = h[2] | ((unsigned)h[3] << 16);
    u.z = h[4] | ((unsigned)h[5] << 16); u.w = h[6] | ((unsigned)h[7] << 16);
    dst[gi] = u;
}

// conv1: Cin=4, f32 NCHW x, stride2 pad1 -> cat1b channels 0..64 (NHWC bf16, stride 100)
__global__ void __launch_bounds__(256) k_conv1(const float* __restrict__ x, const float* __restrict__ w1,
                                               unsigned short* __restrict__ cat1) {
    const int t = blockIdx.x * 256 + threadIdx.x;
    const int oc = t & 63; int idx = t >> 6;
    const int ow = idx & 127; idx >>= 7;
    const int oh = idx & 127; idx >>= 7;
    const int n = idx;
    float a = 0.f;
    #pragma unroll
    for (int c = 0; c < 4; ++c)
    #pragma unroll
    for (int kh = 0; kh < 3; ++kh) {
        const int ih = oh * 2 - 1 + kh;
        if ((unsigned)ih >= 256u) continue;
        #pragma unroll
        for (int kw = 0; kw < 3; ++kw) {
            const int iw = ow * 2 - 1 + kw;
            if ((unsigned)iw >= 256u) continue;
            a = fmaf(x[((size_t)(n * 4 + c) * 256 + ih) * 256 + iw],
                     wq8(w1[((oc * 4 + c) * 3 + kh) * 3 + kw]), a);
        }
    }
    cat1[((size_t)(n * 128 + oh) * 128 + ow) * 100 + oc] = f2bf(wq8(a));
}

__global__ void k_init_feat(unsigned* __restrict__ feat) { feat[threadIdx.x] = encf(-2.0f); }

__global__ void k_fc(const unsigned* __restrict__ feat, const float* __restrict__ wfc,
                     float* __restrict__ out) {
    int n = threadIdx.x;
    if (n < 8) {
        float s = 0.f;
        for (int c = 0; c < 32; ++c) s += decf(feat[n * 32 + c]) * wq8(wfc[c]);
        out[n] = wq8(s);
    }
}

// Implicit-GEMM MFMA conv, NHWC, up to 3 channel-concatenated segments, pad/crop fused.
// T14 staging: issue next-chunk global loads into regs before compute, ds_write after barrier.
// LDS layout: per pixel CHQ/2 16B units, unit u holds cin {32s+4g..+3, 32s+16+4g..+3} (u = s*4+g),
// stored at u^(pix&UM) -> conflict-free b128 reads.
// MODE 0: dst[pix*dstr+dch+oc] = bf16(wq8(y))
// MODE 1: v=(1-wq8(y))*res; optional dstf(f32, stride 512); dsthl hi@oc, lo@512+oc (stride 1024)
// MODE 2: feat[n*32+oc] = max over spatial
template<int K, int STR, int WM, int WN, int BN, int CHQ, int MODE, int RESF>
__global__ void __launch_bounds__(256) k_mconv(
    const unsigned short* __restrict__ s0, int c0n, int st0,
    const unsigned short* __restrict__ s1, int c1n, int st1,
    const unsigned short* __restrict__ s2, int c2n, int st2,
    int S, int padeff,
    const uint4* __restrict__ wqp, int nch32, int noct,
    unsigned short* __restrict__ dst, int dstr, int dch,
    float* __restrict__ dstf, unsigned short* __restrict__ dsthl,
    const void* __restrict__ res, int rstr,
    unsigned* __restrict__ feat,
    int OCv, int OH, int OW, int TILES_W, int nch)
{
    constexpr int TH = WM * 4;
    constexpr int RH = (TH - 1) * STR + K, RW = 7 * STR + K;
    constexpr int NQ = RH * RW * CHQ;
    constexpr int SR = (NQ + 255) / 256;
    constexpr int UPP = CHQ / 2, UM = UPP - 1;
    constexpr int NSL = CHQ / 8;
    __shared__ uint2 ldsq[NQ];
    __shared__ float sred[4][16];
    uint4* lds4 = (uint4*)ldsq;

    const int tid = threadIdx.x;
    const int lane = tid & 63, w = tid >> 6;
    const int wm = w % WM, wn = w / WM;
    const int l15 = lane & 15, g = lane >> 4;
    const int n = blockIdx.z;
    const int tileh = blockIdx.x / TILES_W, tilew = blockIdx.x % TILES_W;
    const int oh0 = tileh * TH, ow0 = tilew * 8;
    const int ih0 = oh0 * STR - padeff, iw0 = ow0 * STR - padeff;
    const int blk_oct0 = blockIdx.y * (WN * BN);
    const int Ctot = c0n + c1n + c2n;

    f32x4 acc[2][BN];
    #pragma unroll
    for (int am = 0; am < 2; ++am)
        #pragma unroll
        for (int bn = 0; bn < BN; ++bn) acc[am][bn] = (f32x4){0.f, 0.f, 0.f, 0.f};

    uint2 ld[SR];
    auto issue = [&](int ch) {
        #pragma unroll
        for (int i = 0; i < SR; ++i) {
            const int idx = tid + i * 256;
            uint2 v; v.x = 0u; v.y = 0u;
            if (idx < NQ) {
                const int q = idx & (CHQ - 1), pix = idx / CHQ;
                const int r = pix / RW, c = pix % RW;
                const int ih = ih0 + r, iw = iw0 + c;
                const int cin = ch * (CHQ * 4) + q * 4;
                if ((unsigned)ih < (unsigned)S && (unsigned)iw < (unsigned)S && cin < Ctot) {
                    const unsigned short* p; int loc, st;
                    if (cin < c0n)            { p = s0; loc = cin;             st = st0; }
                    else if (cin < c0n + c1n) { p = s1; loc = cin - c0n;       st = st1; }
                    else                      { p = s2; loc = cin - c0n - c1n; st = st2; }
                    const size_t pg = ((size_t)n * S + ih) * S + iw;
                    v = *(const uint2*)(p + pg * st + loc);
                }
            }
            ld[i] = v;
        }
    };
    auto commit = [&]() {
        #pragma unroll
        for (int i = 0; i < SR; ++i) {
            const int idx = tid + i * 256;
            if (idx < NQ) {
                const int q = idx & (CHQ - 1), pix = idx / CHQ;
                const int s = q >> 3, qs = q & 7;
                const int unit = s * 4 + (qs & 3), half = qs >> 2;
                ldsq[(size_t)pix * CHQ + ((unit ^ (pix & UM)) << 1) + half] = ld[i];
            }
        }
    };

    issue(0);
    commit();
    for (int ch = 0; ch < nch; ++ch) {
        __syncthreads();
        if (ch + 1 < nch) issue(ch + 1);
        #pragma unroll
        for (int kh = 0; kh < K; ++kh)
        #pragma unroll
        for (int kw = 0; kw < K; ++kw) {
            const int kpos = kh * K + kw;
            #pragma unroll
            for (int s = 0; s < NSL; ++s) {
                const int ch32 = ch * NSL + s;
                short8 bfr[BN];
                #pragma unroll
                for (int bn = 0; bn < BN; ++bn) {
                    union { uint4 u; short8 v; } bu;
                    bu.u = wqp[((size_t)(kpos * nch32 + ch32) * noct + blk_oct0 + wn * BN + bn) * 64 + lane];
                    bfr[bn] = bu.v;
                }
                short8 afr[2];
                #pragma unroll
                for (int am = 0; am < 2; ++am) {
                    const int sp = wm * 32 + am * 16 + l15;
                    const int r = (sp >> 3) * STR + kh, c = (sp & 7) * STR + kw;
                    const int pix = r * RW + c;
                    union { uint4 u; short8 v; } au;
                    au.u = lds4[pix * UPP + ((s * 4 + g) ^ (pix & UM))];
                    afr[am] = au.v;
                }
                #pragma unroll
                for (int am = 0; am < 2; ++am)
                    #pragma unroll
                    for (int bn = 0; bn < BN; ++bn)
                        acc[am][bn] = __builtin_amdgcn_mfma_f32_16x16x32_bf16(afr[am], bfr[bn], acc[am][bn], 0, 0, 0);
            }
        }
        if (ch + 1 < nch) { __syncthreads(); commit(); }
    }

    if (MODE == 2) {
        float m = -2.0f;
        #pragma unroll
        for (int am = 0; am < 2; ++am)
            #pragma unroll
            for (int rg = 0; rg < 4; ++rg) {
                const int sp = wm * 32 + am * 16 + g * 4 + rg;
                const int oh = oh0 + (sp >> 3), ow = ow0 + (sp & 7);
                const float v = (oh < OH && ow < OW) ? wq8(acc[am][0][rg]) : -2.0f;
                m = fmaxf(m, v);
            }
        m = fmaxf(m, __shfl_xor(m, 16));
        m = fmaxf(m, __shfl_xor(m, 32));
        if (lane < 16) sred[w][l15] = m;
        __syncthreads();
        if (tid < 32) {
            const int wn2 = tid >> 4, l = tid & 15;
            float mm = sred[wn2 * WM + 0][l];
            #pragma unroll
            for (int i = 1; i < WM; ++i) mm = fmaxf(mm, sred[wn2 * WM + i][l]);
            atomicMax(&feat[n * 32 + (blk_oct0 + wn2) * 16 + l], encf(mm));
        }
    } else {
        #pragma unroll
        for (int am = 0; am < 2; ++am)
        #pragma unroll
        for (int bn = 0; bn < BN; ++bn)
        #pragma unroll
        for (int rg = 0; rg < 4; ++rg) {
            const int sp = wm * 32 + am * 16 + g * 4 + rg;
            const int oh = oh0 + (sp >> 3), ow = ow0 + (sp & 7);
            const int oc = (blk_oct0 + wn * BN + bn) * 16 + l15;
            if (oh < OH && ow < OW && oc < OCv) {
                const size_t pixo = (size_t)(n * OH + oh) * OW + ow;
                const float y = wq8(acc[am][bn][rg]);
                if (MODE == 0) {
                    dst[pixo * dstr + dch + oc] = f2bf(y);
                } else {
                    const float rv = (RESF == 1) ? bf2f(((const unsigned short*)res)[pixo * rstr + oc])
                                                 : ((const float*)res)[pixo * rstr + oc];
                    const float v = (1.0f - y) * rv;
                    if (dstf) dstf[pixo * 512 + oc] = v;
                    const unsigned short hi = f2bf(v);
                    dsthl[pixo * 1024 + oc] = hi;
                    dsthl[pixo * 1024 + 512 + oc] = f2bf(v - bf2f(hi));
                }
            }
        }
    }
}

extern "C" void kernel_launch(void* const* d_in, const int* in_sizes, int n_in,
                              void* d_out, int out_size, void* d_ws, size_t ws_size,
                              hipStream_t stream)
{
    (void)in_sizes; (void)n_in; (void)out_size; (void)ws_size;
    const float* x = (const float*)d_in[0];
    const float* wfc = (const float*)d_in[16];
    float* out = (float*)d_out;

    char* ws = (char*)d_ws;
    size_t off = 0;
    auto alloc = [&](size_t bytes) { char* p = ws + off; off += (bytes + 255) & ~(size_t)255; return p; };

    // pack descriptors: {w0 idx, OC0, w1 idx(-1 none), OC1, CinW, CinT, K, nch32, noct}
    struct PD { int i0, OC0, i1, OC1, CinW, CinT, K, nch32, noct; };
    static const PD pd[11] = {
        {2, 128, -1, 0,  64,   64, 3,  2,  8},   // 0 conv2
        {3, 256, -1, 0, 128,  128, 3,  4, 16},   // 1 conv3
        {4, 512, -1, 0, 256,  256, 3,  8, 32},   // 2 conv4
        {5, 512, -1, 0, 512,  512, 3, 16, 32},   // 3 r11
        {6, 512, -1, 0, 512,  512, 3, 16, 32},   // 4 r12
        {7, 512, -1, 0, 512, 1024, 3, 32, 32},   // 5 r21 (hi|lo dup)
        {8, 512, -1, 0, 512,  512, 3, 16, 32},   // 6 r22
        {9, 128, 12, 32, 512, 1024, 4, 32, 10},  // 7 L3 = wd3|wu43 (hi|lo dup)
        {10, 64, 13, 32, 416,  416, 4, 14,  6},  // 8 L2 = wd2|wu32
        {11,  4, 14, 32, 224,  224, 4,  8,  3},  // 9 L1 = wd1|wu21
        {15, 32, -1, 0, 100,  100, 4,  4,  2}};  // 10 u10
    uint4* wp[11]; int wtot[11];
    for (int i = 0; i < 11; ++i) {
        wtot[i] = pd[i].K * pd[i].K * pd[i].nch32 * pd[i].noct * 64;
        wp[i] = (uint4*)alloc((size_t)wtot[i] * 16);
    }

    unsigned short* cat1b = (unsigned short*)alloc((size_t)8*128*128*100 * 2);
    unsigned short* cat2b = (unsigned short*)alloc((size_t)8*64*64*224 * 2);
    unsigned short* cat3b = (unsigned short*)alloc((size_t)8*32*32*416 * 2);
    unsigned short* c4b   = (unsigned short*)alloc((size_t)8*16*16*512 * 2);
    unsigned short* r11b  = (unsigned short*)alloc((size_t)8*16*16*512 * 2);   // also r21 out
    float*          r12f  = (float*)alloc((size_t)8*16*16*512 * 4);
    unsigned short* r12hl = (unsigned short*)alloc((size_t)8*16*16*1024 * 2);
    unsigned short* r22hl = (unsigned short*)alloc((size_t)8*16*16*1024 * 2);
    unsigned*       featb = (unsigned*)alloc(256 * 4);

    for (int i = 0; i < 11; ++i) {
        const float* w0 = (const float*)d_in[pd[i].i0];
        const float* w1 = (pd[i].i1 >= 0) ? (const float*)d_in[pd[i].i1] : nullptr;
        k_pack2<<<dim3((wtot[i] + 255) / 256), dim3(256), 0, stream>>>(
            w0, pd[i].OC0, w1, pd[i].OC1, pd[i].CinW, pd[i].CinT, pd[i].K, pd[i].nch32, pd[i].noct, wp[i], wtot[i]);
    }

    k_conv1<<<dim3(8*128*128*64/256), dim3(256), 0, stream>>>(x, (const float*)d_in[1], cat1b);
    k_init_feat<<<dim3(1), dim3(256), 0, stream>>>(featb);

    const unsigned short* nu = nullptr;
    // conv2: c1(cat1b ch0..64) -> cat2b ch0..128
    k_mconv<3,2,2,2,2,8,0,0><<<dim3(64,2,8), 256, 0, stream>>>(
        cat1b,64,100, nu,0,0, nu,0,0, 128,1, wp[0],2,8,
        cat2b,224,0, nullptr,nullptr, nullptr,0, nullptr, 128,64,64,8, 2);
    // conv3: c2 -> cat3b ch0..256
    k_mconv<3,2,2,2,2,8,0,0><<<dim3(16,4,8), 256, 0, stream>>>(
        cat2b,128,224, nu,0,0, nu,0,0, 64,1, wp[1],4,16,
        cat3b,416,0, nullptr,nullptr, nullptr,0, nullptr, 256,32,32,4, 4);
    // conv4: c3 -> c4b
    k_mconv<3,2,2,2,2,8,0,0><<<dim3(4,8,8), 256, 0, stream>>>(
        cat3b,256,416, nu,0,0, nu,0,0, 32,1, wp[2],8,32,
        c4b,512,0, nullptr,nullptr, nullptr,0, nullptr, 512,16,16,2, 4);
    // r11
    k_mconv<3,1,2,2,2,16,0,0><<<dim3(4,8,8), 256, 0, stream>>>(
        c4b,512,512, nu,0,0, nu,0,0, 16,1, wp[3],16,32,
        r11b,512,0, nullptr,nullptr, nullptr,0, nullptr, 512,16,16,2, 8);
    // r12 = (1-q(conv(r11)))*c4 -> r12f + r12hl
    k_mconv<3,1,2,2,2,16,1,1><<<dim3(4,8,8), 256, 0, stream>>>(
        r11b,512,512, nu,0,0, nu,0,0, 16,1, wp[4],16,32,
        nullptr,0,0, r12f,r12hl, c4b,512, nullptr, 512,16,16,2, 8);
    // r21: conv over r12 hi|lo (1024 ch) -> r11b
    k_mconv<3,1,2,2,2,16,0,0><<<dim3(4,8,8), 256, 0, stream>>>(
        r12hl,1024,1024, nu,0,0, nu,0,0, 16,1, wp[5],32,32,
        r11b,512,0, nullptr,nullptr, nullptr,0, nullptr, 512,16,16,2, 16);
    // r22 = (1-q(conv(r21)))*r12 -> r22hl
    k_mconv<3,1,2,2,2,16,1,2><<<dim3(4,8,8), 256, 0, stream>>>(
        r11b,512,512, nu,0,0, nu,0,0, 16,1, wp[6],16,32,
        nullptr,0,0, nullptr,r22hl, r12f,512, nullptr, 512,16,16,2, 8);
    // L3: [d3|f4] from r22 hi|lo -> cat3b ch 256..416
    k_mconv<4,1,2,2,1,16,0,0><<<dim3(16,5,8), 256, 0, stream>>>(
        r22hl,1024,1024, nu,0,0, nu,0,0, 16,10, wp[7],32,10,
        cat3b,416,256, nullptr,nullptr, nullptr,0, nullptr, 160,32,32,4, 16);
    // L2: [d2|f3] from cat3 -> cat2b ch 128..224
    k_mconv<4,1,2,2,1,16,0,0><<<dim3(64,3,8), 256, 0, stream>>>(
        cat3b,416,416, nu,0,0, nu,0,0, 32,18, wp[8],14,6,
        cat2b,224,128, nullptr,nullptr, nullptr,0, nullptr, 96,64,64,8, 7);
    // L1: [d1|f2] from cat2 -> cat1b ch 64..100
    k_mconv<4,1,4,1,1,16,0,0><<<dim3(128,3,8), 256, 0, stream>>>(
        cat2b,224,224, nu,0,0, nu,0,0, 64,34, wp[9],8,3,
        cat1b,100,64, nullptr,nullptr, nullptr,0, nullptr, 36,128,128,16, 4);
    // u10 + fused global max-pool
    k_mconv<4,1,2,2,1,16,2,0><<<dim3(1089,1,8), 256, 0, stream>>>(
        cat1b,100,100, nu,0,0, nu,0,0, 128,66, wp[10],4,2,
        nullptr,0,0, nullptr,nullptr, nullptr,0, featb, 32,257,257,33, 2);
    // FC
    k_fc<<<dim3(1), dim3(64), 0, stream>>>(featb, wfc, out);
}

// Round 5
// 825.512 us; speedup vs baseline: 19.2450x; 1.2113x over previous
//
#include <hip/hip_runtime.h>

#define DEV __device__ __forceinline__

typedef __attribute__((ext_vector_type(8))) short short8;
typedef __attribute__((ext_vector_type(4))) float f32x4;

// WAGE quantizer: clip(round(x*128)/128, +-127/128). rintf = RNE = jnp.round.
DEV float wq8(float x) {
    float q = rintf(x * 128.0f) * 0.0078125f;
    return fminf(fmaxf(q, -0.9921875f), 0.9921875f);
}
DEV unsigned short f2bf(float x) {
    unsigned u = __float_as_uint(x);
    return (unsigned short)((u + 0x7FFFu + ((u >> 16) & 1u)) >> 16);
}
DEV float bf2f(unsigned short h) { return __uint_as_float(((unsigned)h) << 16); }
DEV unsigned encf(float f) { unsigned u = __float_as_uint(f); return (u & 0x80000000u) ? ~u : (u | 0x80000000u); }
DEV float decf(unsigned u) { return (u & 0x80000000u) ? __uint_as_float(u ^ 0x80000000u) : __uint_as_float(~u); }

// async global->LDS, 16B per lane, dest = uniform base + lane*16 (linear)
#define GLOAD16(g, l) __builtin_amdgcn_global_load_lds( \
    (const __attribute__((address_space(1))) void*)(g), \
    (__attribute__((address_space(3))) void*)(l), 16, 0, 0)

// ---------------- fused weight pack (all 11 layers in one launch) ----------------
// B-fragment mapping: element e of lane-group g (lane>>4) = cin ch32*32 + g*8 + e.
// oc = oct*16 + (lane&15). oc >= OC0+OC1 -> zero. cin >= CinT -> zero.
// hi|lo duplicated sources: CinT == 2*CinW, cin >= CinW reads cin-CinW.
struct PackDesc {
    const float* w0; const float* w1; uint4* dst;
    int OC0, OC1, CinW, CinT, K, nch32, noct, nthreads;
};
struct PackArgs { PackDesc d[11]; int bofs[12]; };

__global__ void __launch_bounds__(256) k_packall(PackArgs a) {
    const int b = blockIdx.x;
    int i = 0;
    #pragma unroll
    for (int j = 1; j < 11; ++j) if (b >= a.bofs[j]) i = j;
    const PackDesc D = a.d[i];
    const int gi = (b - a.bofs[i]) * 256 + threadIdx.x;
    if (gi >= D.nthreads) return;
    const int lane = gi & 63; int t = gi >> 6;
    const int oct = t % D.noct; t /= D.noct;
    const int ch = t % D.nch32; const int kpos = t / D.nch32;
    const int kh = kpos / D.K, kw = kpos % D.K;
    const int oc = oct * 16 + (lane & 15), g = lane >> 4;
    const float* src = nullptr; int oci = 0;
    if (oc < D.OC0) { src = D.w0; oci = oc; }
    else if (oc < D.OC0 + D.OC1) { src = D.w1; oci = oc - D.OC0; }
    unsigned short h[8];
    #pragma unroll
    for (int e = 0; e < 8; ++e) {
        const int cin = ch * 32 + g * 8 + e;
        float v = 0.f;
        if (src != nullptr && cin < D.CinT) {
            const int cw = (cin >= D.CinW) ? cin - D.CinW : cin;
            v = wq8(src[((size_t)(oci * D.CinW + cw) * D.K + kh) * D.K + kw]);
        }
        h[e] = f2bf(v);
    }
    uint4 u;
    u.x = h[0] | ((unsigned)h[1] << 16); u.y = h[2] | ((unsigned)h[3] << 16);
    u.z = h[4] | ((unsigned)h[5] << 16); u.w = h[6] | ((unsigned)h[7] << 16);
    D.dst[gi] = u;
}

// ---------------- conv1: LDS-tiled vector conv (exact fmaf chain preserved) ----------------
// block: 8x8 spatial x 64 oc; grid (256 tiles, 8 n). cat1 stride 104, ch 0..63.
__global__ void __launch_bounds__(256) k_conv1(const float* __restrict__ x, const float* __restrict__ w1,
                                               unsigned short* __restrict__ cat1) {
    __shared__ float sw2[36][64];
    __shared__ float sin_[4][17][17];
    const int tid = threadIdx.x;
    const int n = blockIdx.y;
    const int oh0 = (blockIdx.x >> 4) * 8, ow0 = (blockIdx.x & 15) * 8;
    for (int i = tid; i < 2304; i += 256) sw2[i % 36][i / 36] = wq8(w1[i]);
    const int ih0 = oh0 * 2 - 1, iw0 = ow0 * 2 - 1;
    for (int i = tid; i < 4 * 289; i += 256) {
        const int c = i / 289, rem = i % 289, r = rem / 17, cc = rem % 17;
        const int ih = ih0 + r, iw = iw0 + cc;
        float v = 0.f;
        if ((unsigned)ih < 256u && (unsigned)iw < 256u) v = x[((size_t)(n * 4 + c) * 256 + ih) * 256 + iw];
        sin_[c][r][cc] = v;
    }
    __syncthreads();
    const int sp = tid & 63, ocg = tid >> 6;
    const int oh = sp >> 3, ow = sp & 7;
    float acc[16];
    #pragma unroll
    for (int j = 0; j < 16; ++j) acc[j] = 0.f;
    #pragma unroll
    for (int c = 0; c < 4; ++c)
    #pragma unroll
    for (int kh = 0; kh < 3; ++kh)
    #pragma unroll
    for (int kw = 0; kw < 3; ++kw) {
        const float v = sin_[c][oh * 2 + kh][ow * 2 + kw];
        const float4* wp4 = (const float4*)&sw2[c * 9 + kh * 3 + kw][ocg * 16];
        #pragma unroll
        for (int q = 0; q < 4; ++q) {
            const float4 wv = wp4[q];
            acc[q * 4 + 0] = fmaf(v, wv.x, acc[q * 4 + 0]);
            acc[q * 4 + 1] = fmaf(v, wv.y, acc[q * 4 + 1]);
            acc[q * 4 + 2] = fmaf(v, wv.z, acc[q * 4 + 2]);
            acc[q * 4 + 3] = fmaf(v, wv.w, acc[q * 4 + 3]);
        }
    }
    const size_t pix = ((size_t)(n * 128) + oh0 + oh) * 128 + ow0 + ow;
    unsigned uo[8];
    #pragma unroll
    for (int j = 0; j < 8; ++j)
        uo[j] = (unsigned)f2bf(wq8(acc[2 * j])) | ((unsigned)f2bf(wq8(acc[2 * j + 1])) << 16);
    uint4* dp = (uint4*)(cat1 + pix * 104 + ocg * 16);
    uint4 a0; a0.x = uo[0]; a0.y = uo[1]; a0.z = uo[2]; a0.w = uo[3];
    uint4 a1; a1.x = uo[4]; a1.y = uo[5]; a1.z = uo[6]; a1.w = uo[7];
    dp[0] = a0; dp[1] = a1;
}

// feat init + device zero-page (ws is poisoned 0xAA -> must write zeros each launch)
__global__ void k_init(unsigned* __restrict__ feat, uint4* __restrict__ zbuf) {
    feat[threadIdx.x] = encf(-2.0f);
    if (threadIdx.x < 64) { uint4 z; z.x = z.y = z.z = z.w = 0u; zbuf[threadIdx.x] = z; }
}

__global__ void k_fc(const unsigned* __restrict__ feat, const float* __restrict__ wfc,
                     float* __restrict__ out) {
    int n = threadIdx.x;
    if (n < 8) {
        float s = 0.f;
        for (int c = 0; c < 32; ++c) s += decf(feat[n * 32 + c]) * wq8(wfc[c]);
        out[n] = wq8(s);
    }
}

// ---------------- implicit-GEMM MFMA conv ----------------
// Single NHWC source (stride st0 ch, mult of 8), pad/crop fused, gload_lds staging:
// LDS unit u (16B = 8 cin) of pixel pix lives at linear slot pix*UPP + (u^(pix&UM));
// source lane for slot d reads global unit u = (d%UPP)^(pix&UM) -> pre-swizzled source,
// linear LDS dest (rule #21). OOB/pad/cin>=Ctot lanes read zbuf. Double-buffered with
// counted vmcnt + raw s_barrier (T4-lite).
// MODE 0: dst[pix*dstr+dch+oc]=bf16(wq8(y)); MODE 1: v=(1-wq8(y))*res -> dstf(f32,512) and
// dsthl hi/lo (stride 1024); MODE 2: feat = max over spatial.
template<int K, int STR, int WM, int WN, int BN, int CHQ, int MODE, int RESF>
__global__ void __launch_bounds__(256) k_mconv(
    const unsigned short* __restrict__ s0, int Ctot, int st0,
    int S, int padeff,
    const uint4* __restrict__ wqp, int nch32, int noct,
    unsigned short* __restrict__ dst, int dstr, int dch,
    float* __restrict__ dstf, unsigned short* __restrict__ dsthl,
    const void* __restrict__ res, int rstr,
    unsigned* __restrict__ feat,
    const unsigned short* __restrict__ zbuf,
    int OCv, int OH, int OW, int TILES_W, int nch)
{
    constexpr int TH = WM * 4;
    constexpr int RH = (TH - 1) * STR + K, RW = 7 * STR + K;
    constexpr int UPP = CHQ / 2, UM = UPP - 1, NSL = CHQ / 8;
    constexpr int NU = RH * RW * UPP;
    constexpr int ROUNDS = (NU + 255) / 256;
    constexpr int NUP = ROUNDS * 256;
    __shared__ uint4 lds[2 * NUP];
    __shared__ float sred[4][16];

    const int tid = threadIdx.x, lane = tid & 63, w = tid >> 6;
    const int wm = w % WM, wn = w / WM;
    const int l15 = lane & 15, g = lane >> 4;
    const int n = blockIdx.z;
    const int tileh = blockIdx.x / TILES_W, tilew = blockIdx.x % TILES_W;
    const int oh0 = tileh * TH, ow0 = tilew * 8;
    const int ih0 = oh0 * STR - padeff, iw0 = ow0 * STR - padeff;
    const int blk_oct0 = blockIdx.y * (WN * BN);

    f32x4 acc[2][BN];
    #pragma unroll
    for (int am = 0; am < 2; ++am)
        #pragma unroll
        for (int bn = 0; bn < BN; ++bn) acc[am][bn] = (f32x4){0.f, 0.f, 0.f, 0.f};

    auto issue = [&](int ch, int buf) {
        uint4* lb = &lds[buf * NUP];
        #pragma unroll
        for (int rd = 0; rd < ROUNDS; ++rd) {
            const int d = rd * 256 + w * 64 + lane;
            const unsigned short* gp = zbuf;
            if (d < NU) {
                const int pix = d / UPP;
                const int u = (d & UM) ^ (pix & UM);
                const int r = pix / RW, c = pix % RW;
                const int ih = ih0 + r, iw = iw0 + c;
                const int cin = ch * (CHQ * 4) + u * 8;
                if ((unsigned)ih < (unsigned)S && (unsigned)iw < (unsigned)S && cin < Ctot)
                    gp = s0 + (((size_t)n * S + ih) * S + iw) * st0 + cin;
            }
            GLOAD16(gp, lb + rd * 256 + w * 64);
        }
    };

    issue(0, 0);
    for (int ch = 0; ch < nch; ++ch) {
        const int buf = ch & 1;
        if (ch + 1 < nch) {
            issue(ch + 1, buf ^ 1);
            __builtin_amdgcn_s_waitcnt(0xF70 | ROUNDS);   // wait my ch-loads; keep ch+1 in flight
        } else {
            __builtin_amdgcn_s_waitcnt(0xF70);            // vmcnt(0)
        }
        __builtin_amdgcn_s_barrier();
        __builtin_amdgcn_sched_barrier(0);
        const uint4* lb = &lds[buf * NUP];
        #pragma unroll
        for (int kh = 0; kh < K; ++kh)
        #pragma unroll
        for (int kw = 0; kw < K; ++kw) {
            const int kpos = kh * K + kw;
            #pragma unroll
            for (int s = 0; s < NSL; ++s) {
                const int ch32 = ch * NSL + s;
                short8 bfr[BN];
                #pragma unroll
                for (int bn = 0; bn < BN; ++bn) {
                    union { uint4 u; short8 v; } bu;
                    bu.u = wqp[((size_t)(kpos * nch32 + ch32) * noct + blk_oct0 + wn * BN + bn) * 64 + lane];
                    bfr[bn] = bu.v;
                }
                #pragma unroll
                for (int am = 0; am < 2; ++am) {
                    const int sp = wm * 32 + am * 16 + l15;
                    const int r = (sp >> 3) * STR + kh, c = (sp & 7) * STR + kw;
                    const int pix = r * RW + c;
                    union { uint4 u; short8 v; } au;
                    au.u = lb[pix * UPP + ((s * 4 + g) ^ (pix & UM))];
                    #pragma unroll
                    for (int bn = 0; bn < BN; ++bn)
                        acc[am][bn] = __builtin_amdgcn_mfma_f32_16x16x32_bf16(au.v, bfr[bn], acc[am][bn], 0, 0, 0);
                }
            }
        }
        __builtin_amdgcn_sched_barrier(0);
        __builtin_amdgcn_s_barrier();
    }

    if (MODE == 2) {
        float m = -2.0f;
        #pragma unroll
        for (int am = 0; am < 2; ++am)
            #pragma unroll
            for (int rg = 0; rg < 4; ++rg) {
                const int sp = wm * 32 + am * 16 + g * 4 + rg;
                const int oh = oh0 + (sp >> 3), ow = ow0 + (sp & 7);
                const float v = (oh < OH && ow < OW) ? wq8(acc[am][0][rg]) : -2.0f;
                m = fmaxf(m, v);
            }
        m = fmaxf(m, __shfl_xor(m, 16));
        m = fmaxf(m, __shfl_xor(m, 32));
        if (lane < 16) sred[w][l15] = m;
        __syncthreads();
        if (tid < 32) {
            const int wn2 = tid >> 4, l = tid & 15;
            float mm = sred[wn2 * WM + 0][l];
            #pragma unroll
            for (int i = 1; i < WM; ++i) mm = fmaxf(mm, sred[wn2 * WM + i][l]);
            atomicMax(&feat[n * 32 + (blk_oct0 + wn2) * 16 + l], encf(mm));
        }
    } else {
        #pragma unroll
        for (int am = 0; am < 2; ++am)
        #pragma unroll
        for (int bn = 0; bn < BN; ++bn)
        #pragma unroll
        for (int rg = 0; rg < 4; ++rg) {
            const int sp = wm * 32 + am * 16 + g * 4 + rg;
            const int oh = oh0 + (sp >> 3), ow = ow0 + (sp & 7);
            const int oc = (blk_oct0 + wn * BN + bn) * 16 + l15;
            if (oh < OH && ow < OW && oc < OCv) {
                const size_t pixo = (size_t)(n * OH + oh) * OW + ow;
                const float y = wq8(acc[am][bn][rg]);
                if (MODE == 0) {
                    dst[pixo * dstr + dch + oc] = f2bf(y);
                } else {
                    const float rv = (RESF == 1) ? bf2f(((const unsigned short*)res)[pixo * rstr + oc])
                                                 : ((const float*)res)[pixo * rstr + oc];
                    const float v = (1.0f - y) * rv;
                    if (dstf) dstf[pixo * 512 + oc] = v;
                    const unsigned short hi = f2bf(v);
                    dsthl[pixo * 1024 + oc] = hi;
                    dsthl[pixo * 1024 + 512 + oc] = f2bf(v - bf2f(hi));
                }
            }
        }
    }
}

extern "C" void kernel_launch(void* const* d_in, const int* in_sizes, int n_in,
                              void* d_out, int out_size, void* d_ws, size_t ws_size,
                              hipStream_t stream)
{
    (void)in_sizes; (void)n_in; (void)out_size; (void)ws_size;
    const float* x = (const float*)d_in[0];
    const float* wfc = (const float*)d_in[16];
    float* out = (float*)d_out;

    char* ws = (char*)d_ws;
    size_t off = 0;
    auto alloc = [&](size_t bytes) { char* p = ws + off; off += (bytes + 255) & ~(size_t)255; return p; };

    // pack descriptors: {w0 idx, OC0, w1 idx, OC1, CinW, CinT, K, nch32, noct}
    struct PH { int i0, OC0, i1, OC1, CinW, CinT, K, nch32, noct; };
    static const PH ph[11] = {
        {2, 128, -1, 0,  64,   64, 3,  2,  8},   // 0 conv2
        {3, 256, -1, 0, 128,  128, 3,  4, 16},   // 1 conv3
        {4, 512, -1, 0, 256,  256, 3,  8, 32},   // 2 conv4
        {5, 512, -1, 0, 512,  512, 3, 16, 32},   // 3 r11
        {6, 512, -1, 0, 512,  512, 3, 16, 32},   // 4 r12
        {7, 512, -1, 0, 512, 1024, 3, 32, 32},   // 5 r21 (hi|lo dup)
        {8, 512, -1, 0, 512,  512, 3, 16, 32},   // 6 r22
        {9, 128, 12, 32, 512, 1024, 4, 32, 10},  // 7 L3 = wd3|wu43 (hi|lo dup)
        {10, 64, 13, 32, 416,  416, 4, 14,  6},  // 8 L2 = wd2|wu32
        {11,  4, 14, 32, 224,  224, 4,  8,  3},  // 9 L1 = wd1|wu21 (+4 zero oc -> cat1 pad)
        {15, 32, -1, 0, 100,  100, 4,  4,  2}};  // 10 u10

    PackArgs pa;
    int bacc = 0;
    uint4* wp[11];
    for (int i = 0; i < 11; ++i) {
        const int nthr = ph[i].K * ph[i].K * ph[i].nch32 * ph[i].noct * 64;
        wp[i] = (uint4*)alloc((size_t)nthr * 16);
        pa.d[i].w0 = (const float*)d_in[ph[i].i0];
        pa.d[i].w1 = (ph[i].i1 >= 0) ? (const float*)d_in[ph[i].i1] : nullptr;
        pa.d[i].dst = wp[i];
        pa.d[i].OC0 = ph[i].OC0; pa.d[i].OC1 = ph[i].OC1;
        pa.d[i].CinW = ph[i].CinW; pa.d[i].CinT = ph[i].CinT;
        pa.d[i].K = ph[i].K; pa.d[i].nch32 = ph[i].nch32; pa.d[i].noct = ph[i].noct;
        pa.d[i].nthreads = nthr;
        pa.bofs[i] = bacc;
        bacc += (nthr + 255) / 256;
    }
    pa.bofs[11] = bacc;

    unsigned short* cat1b = (unsigned short*)alloc((size_t)8*128*128*104 * 2);  // c1|d1|f2|pad4
    unsigned short* cat2b = (unsigned short*)alloc((size_t)8*64*64*224 * 2);    // c2|d2|f3
    unsigned short* cat3b = (unsigned short*)alloc((size_t)8*32*32*416 * 2);    // c3|d3|f4
    unsigned short* c4b   = (unsigned short*)alloc((size_t)8*16*16*512 * 2);
    unsigned short* r11b  = (unsigned short*)alloc((size_t)8*16*16*512 * 2);    // also r21 out
    float*          r12f  = (float*)alloc((size_t)8*16*16*512 * 4);
    unsigned short* r12hl = (unsigned short*)alloc((size_t)8*16*16*1024 * 2);
    unsigned short* r22hl = (unsigned short*)alloc((size_t)8*16*16*1024 * 2);
    unsigned*       featb = (unsigned*)alloc(256 * 4);
    uint4*          zbuf  = (uint4*)alloc(1024);

    k_packall<<<dim3((unsigned)bacc), dim3(256), 0, stream>>>(pa);
    k_init<<<dim3(1), dim3(256), 0, stream>>>(featb, zbuf);
    k_conv1<<<dim3(256, 8), dim3(256), 0, stream>>>(x, (const float*)d_in[1], cat1b);

    const unsigned short* zb = (const unsigned short*)zbuf;
    // conv2: cat1 ch0..64 -> cat2 ch0..128
    k_mconv<3,2,2,2,2,8,0,0><<<dim3(64,2,8), 256, 0, stream>>>(
        cat1b,64,104, 128,1, wp[0],2,8,  cat2b,224,0, nullptr,nullptr, nullptr,0, nullptr, zb, 128,64,64,8, 2);
    // conv3: cat2 ch0..128 -> cat3 ch0..256
    k_mconv<3,2,2,2,1,8,0,0><<<dim3(16,8,8), 256, 0, stream>>>(
        cat2b,128,224, 64,1, wp[1],4,16, cat3b,416,0, nullptr,nullptr, nullptr,0, nullptr, zb, 256,32,32,4, 4);
    // conv4: cat3 ch0..256 -> c4
    k_mconv<3,2,2,2,1,8,0,0><<<dim3(4,16,8), 256, 0, stream>>>(
        cat3b,256,416, 32,1, wp[2],8,32, c4b,512,0, nullptr,nullptr, nullptr,0, nullptr, zb, 512,16,16,2, 8);
    // r11
    k_mconv<3,1,2,2,1,16,0,0><<<dim3(4,16,8), 256, 0, stream>>>(
        c4b,512,512, 16,1, wp[3],16,32, r11b,512,0, nullptr,nullptr, nullptr,0, nullptr, zb, 512,16,16,2, 8);
    // r12 = (1-q(conv(r11)))*c4 -> r12f + r12hl
    k_mconv<3,1,2,2,1,16,1,1><<<dim3(4,16,8), 256, 0, stream>>>(
        r11b,512,512, 16,1, wp[4],16,32, nullptr,0,0, r12f,r12hl, c4b,512, nullptr, zb, 512,16,16,2, 8);
    // r21: conv over r12 hi|lo (1024 ch) -> r11b
    k_mconv<3,1,2,2,1,16,0,0><<<dim3(4,16,8), 256, 0, stream>>>(
        r12hl,1024,1024, 16,1, wp[5],32,32, r11b,512,0, nullptr,nullptr, nullptr,0, nullptr, zb, 512,16,16,2, 16);
    // r22 = (1-q(conv(r21)))*r12 -> r22hl
    k_mconv<3,1,2,2,1,16,1,2><<<dim3(4,16,8), 256, 0, stream>>>(
        r11b,512,512, 16,1, wp[6],16,32, nullptr,0,0, nullptr,r22hl, r12f,512, nullptr, zb, 512,16,16,2, 8);
    // L3: [d3|f4] from r22 hi|lo -> cat3 ch 256..416
    k_mconv<4,1,2,2,1,16,0,0><<<dim3(16,5,8), 256, 0, stream>>>(
        r22hl,1024,1024, 16,10, wp[7],32,10, cat3b,416,256, nullptr,nullptr, nullptr,0, nullptr, zb, 160,32,32,4, 16);
    // L2: [d2|f3] from cat3 -> cat2 ch 128..224
    k_mconv<4,1,2,2,1,16,0,0><<<dim3(64,3,8), 256, 0, stream>>>(
        cat3b,416,416, 32,18, wp[8],14,6, cat2b,224,128, nullptr,nullptr, nullptr,0, nullptr, zb, 96,64,64,8, 7);
    // L1: [d1|f2|zero-pad] from cat2 -> cat1 ch 64..104
    k_mconv<4,1,4,1,1,16,0,0><<<dim3(128,3,8), 256, 0, stream>>>(
        cat2b,224,224, 64,34, wp[9],8,3, cat1b,104,64, nullptr,nullptr, nullptr,0, nullptr, zb, 40,128,128,16, 4);
    // u10 + fused global max-pool
    k_mconv<4,1,2,2,1,16,2,0><<<dim3(1089,1,8), 256, 0, stream>>>(
        cat1b,104,104, 128,66, wp[10],4,2, nullptr,0,0, nullptr,nullptr, nullptr,0, featb, zb, 32,257,257,33, 2);
    // FC
    k_fc<<<dim3(1), dim3(64), 0, stream>>>(featb, wfc, out);
}

// Round 7
// 699.647 us; speedup vs baseline: 22.7072x; 1.1799x over previous
//
#include <hip/hip_runtime.h>

#define DEV __device__ __forceinline__

typedef __attribute__((ext_vector_type(8))) short short8;
typedef __attribute__((ext_vector_type(4))) float f32x4;

// WAGE quantizer: clip(round(x*128)/128, +-127/128). rintf = RNE = jnp.round.
DEV float wq8(float x) {
    float q = rintf(x * 128.0f) * 0.0078125f;
    return fminf(fmaxf(q, -0.9921875f), 0.9921875f);
}
DEV unsigned short f2bf(float x) {
    unsigned u = __float_as_uint(x);
    return (unsigned short)((u + 0x7FFFu + ((u >> 16) & 1u)) >> 16);
}
DEV float bf2f(unsigned short h) { return __uint_as_float(((unsigned)h) << 16); }
DEV unsigned encf(float f) { unsigned u = __float_as_uint(f); return (u & 0x80000000u) ? ~u : (u | 0x80000000u); }
DEV float decf(unsigned u) { return (u & 0x80000000u) ? __uint_as_float(u ^ 0x80000000u) : __uint_as_float(~u); }

// async global->LDS, 16B per lane, dest = uniform base + lane*16 (linear)
#define GLOAD16(g, l) __builtin_amdgcn_global_load_lds( \
    (const __attribute__((address_space(1))) void*)(g), \
    (__attribute__((address_space(3))) void*)(l), 16, 0, 0)

// ---------------- fused weight pack (all 11 layers in one launch) ----------------
// B-fragment mapping: element e of lane-group g (lane>>4) = cin ch32*32 + g*8 + e.
// oc = oct*16 + (lane&15). oc >= OC0+OC1 -> zero. cin >= CinT -> zero.
// hi|lo duplicated sources: CinT == 2*CinW, cin >= CinW reads cin-CinW.
struct PackDesc {
    const float* w0; const float* w1; uint4* dst;
    int OC0, OC1, CinW, CinT, K, nch32, noct, nthreads;
};
struct PackArgs { PackDesc d[11]; int bofs[12]; };

__global__ void __launch_bounds__(256) k_packall(PackArgs a) {
    const int b = blockIdx.x;
    int i = 0;
    #pragma unroll
    for (int j = 1; j < 11; ++j) if (b >= a.bofs[j]) i = j;
    const PackDesc D = a.d[i];
    const int gi = (b - a.bofs[i]) * 256 + threadIdx.x;
    if (gi >= D.nthreads) return;
    const int lane = gi & 63; int t = gi >> 6;
    const int oct = t % D.noct; t /= D.noct;
    const int ch = t % D.nch32; const int kpos = t / D.nch32;
    const int kh = kpos / D.K, kw = kpos % D.K;
    const int oc = oct * 16 + (lane & 15), g = lane >> 4;
    const float* src = nullptr; int oci = 0;
    if (oc < D.OC0) { src = D.w0; oci = oc; }
    else if (oc < D.OC0 + D.OC1) { src = D.w1; oci = oc - D.OC0; }
    unsigned short h[8];
    #pragma unroll
    for (int e = 0; e < 8; ++e) {
        const int cin = ch * 32 + g * 8 + e;
        float v = 0.f;
        if (src != nullptr && cin < D.CinT) {
            const int cw = (cin >= D.CinW) ? cin - D.CinW : cin;
            v = wq8(src[((size_t)(oci * D.CinW + cw) * D.K + kh) * D.K + kw]);
        }
        h[e] = f2bf(v);
    }
    uint4 u;
    u.x = h[0] | ((unsigned)h[1] << 16); u.y = h[2] | ((unsigned)h[3] << 16);
    u.z = h[4] | ((unsigned)h[5] << 16); u.w = h[6] | ((unsigned)h[7] << 16);
    D.dst[gi] = u;
}

// ---------------- conv1: LDS-tiled vector conv (exact fmaf chain preserved) ----------------
__global__ void __launch_bounds__(256) k_conv1(const float* __restrict__ x, const float* __restrict__ w1,
                                               unsigned short* __restrict__ cat1) {
    __shared__ float sw2[36][64];
    __shared__ float sin_[4][17][17];
    const int tid = threadIdx.x;
    const int n = blockIdx.y;
    const int oh0 = (blockIdx.x >> 4) * 8, ow0 = (blockIdx.x & 15) * 8;
    for (int i = tid; i < 2304; i += 256) sw2[i % 36][i / 36] = wq8(w1[i]);
    const int ih0 = oh0 * 2 - 1, iw0 = ow0 * 2 - 1;
    for (int i = tid; i < 4 * 289; i += 256) {
        const int c = i / 289, rem = i % 289, r = rem / 17, cc = rem % 17;
        const int ih = ih0 + r, iw = iw0 + cc;
        float v = 0.f;
        if ((unsigned)ih < 256u && (unsigned)iw < 256u) v = x[((size_t)(n * 4 + c) * 256 + ih) * 256 + iw];
        sin_[c][r][cc] = v;
    }
    __syncthreads();
    const int sp = tid & 63, ocg = tid >> 6;
    const int oh = sp >> 3, ow = sp & 7;
    float acc[16];
    #pragma unroll
    for (int j = 0; j < 16; ++j) acc[j] = 0.f;
    #pragma unroll
    for (int c = 0; c < 4; ++c)
    #pragma unroll
    for (int kh = 0; kh < 3; ++kh)
    #pragma unroll
    for (int kw = 0; kw < 3; ++kw) {
        const float v = sin_[c][oh * 2 + kh][ow * 2 + kw];
        const float4* wp4 = (const float4*)&sw2[c * 9 + kh * 3 + kw][ocg * 16];
        #pragma unroll
        for (int q = 0; q < 4; ++q) {
            const float4 wv = wp4[q];
            acc[q * 4 + 0] = fmaf(v, wv.x, acc[q * 4 + 0]);
            acc[q * 4 + 1] = fmaf(v, wv.y, acc[q * 4 + 1]);
            acc[q * 4 + 2] = fmaf(v, wv.z, acc[q * 4 + 2]);
            acc[q * 4 + 3] = fmaf(v, wv.w, acc[q * 4 + 3]);
        }
    }
    const size_t pix = ((size_t)(n * 128) + oh0 + oh) * 128 + ow0 + ow;
    unsigned uo[8];
    #pragma unroll
    for (int j = 0; j < 8; ++j)
        uo[j] = (unsigned)f2bf(wq8(acc[2 * j])) | ((unsigned)f2bf(wq8(acc[2 * j + 1])) << 16);
    uint4* dp = (uint4*)(cat1 + pix * 104 + ocg * 16);
    uint4 a0; a0.x = uo[0]; a0.y = uo[1]; a0.z = uo[2]; a0.w = uo[3];
    uint4 a1; a1.x = uo[4]; a1.y = uo[5]; a1.z = uo[6]; a1.w = uo[7];
    dp[0] = a0; dp[1] = a1;
}

// feat init + device zero-page (ws is poisoned 0xAA -> must write zeros each launch)
__global__ void k_init(unsigned* __restrict__ feat, uint4* __restrict__ zbuf) {
    feat[threadIdx.x] = encf(-2.0f);
    if (threadIdx.x < 64) { uint4 z; z.x = z.y = z.z = z.w = 0u; zbuf[threadIdx.x] = z; }
}

__global__ void k_fc(const unsigned* __restrict__ feat, const float* __restrict__ wfc,
                     float* __restrict__ out) {
    int n = threadIdx.x;
    if (n < 8) {
        float s = 0.f;
        for (int c = 0; c < 32; ++c) s += decf(feat[n * 32 + c]) * wq8(wfc[c]);
        out[n] = wq8(s);
    }
}

// ---------------- implicit-GEMM MFMA conv ----------------
// 1D grid, XCD-chunk swizzle: work = (b&7)*swzq + (b>>3)  (total % 8 == 0 always).
// Work order: ocg innermost, then tile, then n -> each XCD chunk = one n, ocg-groups
// and adjacent tiles share that XCD's L2.
// Staging: gload_lds 16B/lane, linear dest, pre-swizzled source (u = (d%UPP)^(pix&UM)),
// NBUF-deep pipeline with counted vmcnt (never 0 mid-loop).
// MODE 0: dst[pix*dstr+dch+oc]=bf16(wq8(y)); MODE 1: v=(1-wq8(y))*res -> dstf(f32,512)
// and dsthl hi/lo (stride 1024); MODE 2: feat = max over spatial.
template<int K, int STR, int WM, int WN, int BN, int CHQ, int NBUF, int MODE, int RESF>
__global__ void __launch_bounds__(256) k_mconv(
    const unsigned short* __restrict__ s0, int Ctot, int st0,
    int S, int padeff,
    const uint4* __restrict__ wqp, int nch32, int noct,
    unsigned short* __restrict__ dst, int dstr, int dch,
    float* __restrict__ dstf, unsigned short* __restrict__ dsthl,
    const void* __restrict__ res, int rstr,
    unsigned* __restrict__ feat,
    const unsigned short* __restrict__ zbuf,
    int OCv, int OH, int OW, int TILES_W, int nch,
    int NT, int NOCG, int swzq)
{
    constexpr int TH = WM * 4;
    constexpr int RH = (TH - 1) * STR + K, RW = 7 * STR + K;
    constexpr int UPP = CHQ / 2, UM = UPP - 1, NSL = CHQ / 8;
    constexpr int NU = RH * RW * UPP;
    constexpr int ROUNDS = (NU + 255) / 256;
    constexpr int NUP = ROUNDS * 256;
    constexpr int AHEAD = NBUF - 1;
    __shared__ uint4 lds[NBUF * NUP];
    __shared__ float sred[4][16];

    const int tid = threadIdx.x, lane = tid & 63, w = tid >> 6;
    const int wm = w % WM, wn = w / WM;
    const int l15 = lane & 15, g = lane >> 4;

    const int b = blockIdx.x;
    const int work = (b & 7) * swzq + (b >> 3);
    const int ocg = work % NOCG; const int t2 = work / NOCG;
    const int tile = t2 % NT; const int n = t2 / NT;

    const int tileh = tile / TILES_W, tilew = tile % TILES_W;
    const int oh0 = tileh * TH, ow0 = tilew * 8;
    const int ih0 = oh0 * STR - padeff, iw0 = ow0 * STR - padeff;
    const int blk_oct0 = ocg * (WN * BN);

    f32x4 acc[2][BN];
    #pragma unroll
    for (int am = 0; am < 2; ++am)
        #pragma unroll
        for (int bn = 0; bn < BN; ++bn) acc[am][bn] = (f32x4){0.f, 0.f, 0.f, 0.f};

    auto issue = [&](int ch, int buf) {
        uint4* lb = &lds[buf * NUP];
        #pragma unroll
        for (int rd = 0; rd < ROUNDS; ++rd) {
            const int d = rd * 256 + w * 64 + lane;
            const unsigned short* gp = zbuf;
            if (d < NU) {
                const int pix = d / UPP;
                const int u = (d & UM) ^ (pix & UM);
                const int r = pix / RW, c = pix % RW;
                const int ih = ih0 + r, iw = iw0 + c;
                const int cin = ch * (CHQ * 4) + u * 8;
                if ((unsigned)ih < (unsigned)S && (unsigned)iw < (unsigned)S && cin < Ctot)
                    gp = s0 + (((size_t)n * S + ih) * S + iw) * st0 + cin;
            }
            GLOAD16(gp, lb + rd * 256 + w * 64);
        }
    };

    #pragma unroll
    for (int i = 0; i < AHEAD; ++i) if (i < nch) issue(i, i % NBUF);

    for (int ch = 0; ch < nch; ++ch) {
        if (ch + AHEAD < nch) issue(ch + AHEAD, (ch + AHEAD) % NBUF);
        const int infl = (nch - 1 - ch < AHEAD) ? nch - 1 - ch : AHEAD;
        if (infl >= 2)      __builtin_amdgcn_s_waitcnt(0xF70 | (2 * ROUNDS));
        else if (infl == 1) __builtin_amdgcn_s_waitcnt(0xF70 | ROUNDS);
        else                __builtin_amdgcn_s_waitcnt(0xF70);
        __builtin_amdgcn_s_barrier();
        __builtin_amdgcn_sched_barrier(0);
        const uint4* lb = &lds[(ch % NBUF) * NUP];
        #pragma unroll
        for (int kh = 0; kh < K; ++kh)
        #pragma unroll
        for (int kw = 0; kw < K; ++kw) {
            const int kpos = kh * K + kw;
            #pragma unroll
            for (int s = 0; s < NSL; ++s) {
                const int ch32 = ch * NSL + s;
                short8 bfr[BN];
                #pragma unroll
                for (int bn = 0; bn < BN; ++bn) {
                    union { uint4 u; short8 v; } bu;
                    bu.u = wqp[((size_t)(kpos * nch32 + ch32) * noct + blk_oct0 + wn * BN + bn) * 64 + lane];
                    bfr[bn] = bu.v;
                }
                #pragma unroll
                for (int am = 0; am < 2; ++am) {
                    const int sp = wm * 32 + am * 16 + l15;
                    const int r = (sp >> 3) * STR + kh, c = (sp & 7) * STR + kw;
                    const int pix = r * RW + c;
                    union { uint4 u; short8 v; } au;
                    au.u = lb[pix * UPP + ((s * 4 + g) ^ (pix & UM))];
                    #pragma unroll
                    for (int bn = 0; bn < BN; ++bn)
                        acc[am][bn] = __builtin_amdgcn_mfma_f32_16x16x32_bf16(au.v, bfr[bn], acc[am][bn], 0, 0, 0);
                }
            }
        }
        __builtin_amdgcn_sched_barrier(0);
        __builtin_amdgcn_s_barrier();
    }

    if (MODE == 2) {
        float m = -2.0f;
        #pragma unroll
        for (int am = 0; am < 2; ++am)
            #pragma unroll
            for (int rg = 0; rg < 4; ++rg) {
                const int sp = wm * 32 + am * 16 + g * 4 + rg;
                const int oh = oh0 + (sp >> 3), ow = ow0 + (sp & 7);
                const float v = (oh < OH && ow < OW) ? wq8(acc[am][0][rg]) : -2.0f;
                m = fmaxf(m, v);
            }
        m = fmaxf(m, __shfl_xor(m, 16));
        m = fmaxf(m, __shfl_xor(m, 32));
        if (lane < 16) sred[w][l15] = m;
        __syncthreads();
        if (tid < 32) {
            const int wn2 = tid >> 4, l = tid & 15;
            float mm = sred[wn2 * WM + 0][l];
            #pragma unroll
            for (int i = 1; i < WM; ++i) mm = fmaxf(mm, sred[wn2 * WM + i][l]);
            atomicMax(&feat[n * 32 + (blk_oct0 + wn2) * 16 + l], encf(mm));
        }
    } else {
        #pragma unroll
        for (int am = 0; am < 2; ++am)
        #pragma unroll
        for (int bn = 0; bn < BN; ++bn)
        #pragma unroll
        for (int rg = 0; rg < 4; ++rg) {
            const int sp = wm * 32 + am * 16 + g * 4 + rg;
            const int oh = oh0 + (sp >> 3), ow = ow0 + (sp & 7);
            const int oc = (blk_oct0 + wn * BN + bn) * 16 + l15;
            if (oh < OH && ow < OW && oc < OCv) {
                const size_t pixo = (size_t)(n * OH + oh) * OW + ow;
                const float y = wq8(acc[am][bn][rg]);
                if (MODE == 0) {
                    dst[pixo * dstr + dch + oc] = f2bf(y);
                } else {
                    const float rv = (RESF == 1) ? bf2f(((const unsigned short*)res)[pixo * rstr + oc])
                                                 : ((const float*)res)[pixo * rstr + oc];
                    const float v = (1.0f - y) * rv;
                    if (dstf) dstf[pixo * 512 + oc] = v;
                    const unsigned short hi = f2bf(v);
                    dsthl[pixo * 1024 + oc] = hi;
                    dsthl[pixo * 1024 + 512 + oc] = f2bf(v - bf2f(hi));
                }
            }
        }
    }
}

extern "C" void kernel_launch(void* const* d_in, const int* in_sizes, int n_in,
                              void* d_out, int out_size, void* d_ws, size_t ws_size,
                              hipStream_t stream)
{
    (void)in_sizes; (void)n_in; (void)out_size; (void)ws_size;
    const float* x = (const float*)d_in[0];
    const float* wfc = (const float*)d_in[16];
    float* out = (float*)d_out;

    char* ws = (char*)d_ws;
    size_t off = 0;
    auto alloc = [&](size_t bytes) { char* p = ws + off; off += (bytes + 255) & ~(size_t)255; return p; };

    // pack descriptors: {w0 idx, OC0, w1 idx, OC1, CinW, CinT, K, nch32, noct}
    struct PH { int i0, OC0, i1, OC1, CinW, CinT, K, nch32, noct; };
    static const PH ph[11] = {
        {2, 128, -1, 0,  64,   64, 3,  2,  8},   // 0 conv2
        {3, 256, -1, 0, 128,  128, 3,  4, 16},   // 1 conv3
        {4, 512, -1, 0, 256,  256, 3,  8, 32},   // 2 conv4
        {5, 512, -1, 0, 512,  512, 3, 16, 32},   // 3 r11
        {6, 512, -1, 0, 512,  512, 3, 16, 32},   // 4 r12
        {7, 512, -1, 0, 512, 1024, 3, 32, 32},   // 5 r21 (hi|lo dup)
        {8, 512, -1, 0, 512,  512, 3, 16, 32},   // 6 r22
        {9, 128, 12, 32, 512, 1024, 4, 32, 10},  // 7 L3 = wd3|wu43 (hi|lo dup)
        {10, 64, 13, 32, 416,  416, 4, 14,  6},  // 8 L2 = wd2|wu32
        {11,  4, 14, 32, 224,  224, 4,  8,  3},  // 9 L1 = wd1|wu21 (+4 zero oc -> cat1 pad)
        {15, 32, -1, 0, 100,  100, 4,  4,  2}};  // 10 u10

    PackArgs pa;
    int bacc = 0;
    uint4* wp[11];
    for (int i = 0; i < 11; ++i) {
        const int nthr = ph[i].K * ph[i].K * ph[i].nch32 * ph[i].noct * 64;
        wp[i] = (uint4*)alloc((size_t)nthr * 16);
        pa.d[i].w0 = (const float*)d_in[ph[i].i0];
        pa.d[i].w1 = (ph[i].i1 >= 0) ? (const float*)d_in[ph[i].i1] : nullptr;
        pa.d[i].dst = wp[i];
        pa.d[i].OC0 = ph[i].OC0; pa.d[i].OC1 = ph[i].OC1;
        pa.d[i].CinW = ph[i].CinW; pa.d[i].CinT = ph[i].CinT;
        pa.d[i].K = ph[i].K; pa.d[i].nch32 = ph[i].nch32; pa.d[i].noct = ph[i].noct;
        pa.d[i].nthreads = nthr;
        pa.bofs[i] = bacc;
        bacc += (nthr + 255) / 256;
    }
    pa.bofs[11] = bacc;

    unsigned short* cat1b = (unsigned short*)alloc((size_t)8*128*128*104 * 2);  // c1|d1|f2|pad4
    unsigned short* cat2b = (unsigned short*)alloc((size_t)8*64*64*224 * 2);    // c2|d2|f3
    unsigned short* cat3b = (unsigned short*)alloc((size_t)8*32*32*416 * 2);    // c3|d3|f4
    unsigned short* c4b   = (unsigned short*)alloc((size_t)8*16*16*512 * 2);
    unsigned short* r11b  = (unsigned short*)alloc((size_t)8*16*16*512 * 2);    // also r21 out
    float*          r12f  = (float*)alloc((size_t)8*16*16*512 * 4);
    unsigned short* r12hl = (unsigned short*)alloc((size_t)8*16*16*1024 * 2);
    unsigned short* r22hl = (unsigned short*)alloc((size_t)8*16*16*1024 * 2);
    unsigned*       featb = (unsigned*)alloc(256 * 4);
    uint4*          zbuf  = (uint4*)alloc(1024);

    k_packall<<<dim3((unsigned)bacc), dim3(256), 0, stream>>>(pa);
    k_init<<<dim3(1), dim3(256), 0, stream>>>(featb, zbuf);
    k_conv1<<<dim3(256, 8), dim3(256), 0, stream>>>(x, (const float*)d_in[1], cat1b);

    const unsigned short* zb = (const unsigned short*)zbuf;

    // conv2: cat1 ch0..64 -> cat2 ch0..128      NT=64 NOCG=2 total=1024 swzq=128
    k_mconv<3,2,2,2,2,8,2,0,0><<<dim3(1024), 256, 0, stream>>>(
        cat1b,64,104, 128,1, wp[0],2,8,  cat2b,224,0, nullptr,nullptr, nullptr,0, nullptr, zb,
        128,64,64,8, 2, 64,2,128);
    // conv3: cat2 ch0..128 -> cat3 ch0..256     NT=16 NOCG=8 total=1024 swzq=128
    k_mconv<3,2,2,2,1,8,2,0,0><<<dim3(1024), 256, 0, stream>>>(
        cat2b,128,224, 64,1, wp[1],4,16, cat3b,416,0, nullptr,nullptr, nullptr,0, nullptr, zb,
        256,32,32,4, 4, 16,8,128);
    // conv4: cat3 ch0..256 -> c4                NT=4 NOCG=16 total=512 swzq=64
    k_mconv<3,2,2,2,1,8,2,0,0><<<dim3(512), 256, 0, stream>>>(
        cat3b,256,416, 32,1, wp[2],8,32, c4b,512,0, nullptr,nullptr, nullptr,0, nullptr, zb,
        512,16,16,2, 8, 4,16,64);
    // r11                                       NT=4 NOCG=16 total=512 swzq=64
    k_mconv<3,1,2,2,1,16,3,0,0><<<dim3(512), 256, 0, stream>>>(
        c4b,512,512, 16,1, wp[3],16,32, r11b,512,0, nullptr,nullptr, nullptr,0, nullptr, zb,
        512,16,16,2, 8, 4,16,64);
    // r12 = (1-q(conv(r11)))*c4 -> r12f + r12hl
    k_mconv<3,1,2,2,1,16,3,1,1><<<dim3(512), 256, 0, stream>>>(
        r11b,512,512, 16,1, wp[4],16,32, nullptr,0,0, r12f,r12hl, c4b,512, nullptr, zb,
        512,16,16,2, 8, 4,16,64);
    // r21: conv over r12 hi|lo (1024 ch) -> r11b
    k_mconv<3,1,2,2,1,16,3,0,0><<<dim3(512), 256, 0, stream>>>(
        r12hl,1024,1024, 16,1, wp[5],32,32, r11b,512,0, nullptr,nullptr, nullptr,0, nullptr, zb,
        512,16,16,2, 16, 4,16,64);
    // r22 = (1-q(conv(r21)))*r12 -> r22hl
    k_mconv<3,1,2,2,1,16,3,1,2><<<dim3(512), 256, 0, stream>>>(
        r11b,512,512, 16,1, wp[6],16,32, nullptr,0,0, nullptr,r22hl, r12f,512, nullptr, zb,
        512,16,16,2, 8, 4,16,64);
    // L3: [d3|f4] from r22 hi|lo -> cat3 ch 256..416   NT=16 NOCG=5 total=640 swzq=80
    k_mconv<4,1,2,2,1,16,3,0,0><<<dim3(640), 256, 0, stream>>>(
        r22hl,1024,1024, 16,10, wp[7],32,10, cat3b,416,256, nullptr,nullptr, nullptr,0, nullptr, zb,
        160,32,32,4, 16, 16,5,80);
    // L2: [d2|f3] from cat3 -> cat2 ch 128..224        NT=64 NOCG=3 total=1536 swzq=192
    k_mconv<4,1,2,2,1,16,3,0,0><<<dim3(1536), 256, 0, stream>>>(
        cat3b,416,416, 32,18, wp[8],14,6, cat2b,224,128, nullptr,nullptr, nullptr,0, nullptr, zb,
        96,64,64,8, 7, 64,3,192);
    // L1: [d1|f2|zero-pad] from cat2 -> cat1 ch 64..104  NT=128 NOCG=3 total=3072 swzq=384
    k_mconv<4,1,4,1,1,16,2,0,0><<<dim3(3072), 256, 0, stream>>>(
        cat2b,224,224, 64,34, wp[9],8,3, cat1b,104,64, nullptr,nullptr, nullptr,0, nullptr, zb,
        40,128,128,16, 4, 128,3,384);
    // u10 + fused global max-pool                     NT=1089 NOCG=1 total=8712 swzq=1089
    k_mconv<4,1,2,2,1,16,2,2,0><<<dim3(8712), 256, 0, stream>>>(
        cat1b,104,104, 128,66, wp[10],4,2, nullptr,0,0, nullptr,nullptr, nullptr,0, featb, zb,
        32,257,257,33, 2, 1089,1,1089);
    // FC
    k_fc<<<dim3(1), dim3(64), 0, stream>>>(featb, wfc, out);
}